// Round 20
// baseline (409.676 us; speedup 1.0000x reference)
//
#include <hip/hip_runtime.h>
#include <hip/hip_bf16.h>

// GNN_84043920048593: hetero SAGEConv. f32 I/O.
// R19: MFMA bf16 epis -> 409us; top = gathers (random 256B f32 rows, LLC-
// bound). R20: bf16 node tables (prep cvt) + bf16 agg end-to-end — halves
// every random byte. Epis consume bf16 directly (same MFMA path as R19).

typedef unsigned int u32;
typedef unsigned char u8;
typedef unsigned short u16b;
typedef short short8 __attribute__((ext_vector_type(8)));
typedef float f32x4 __attribute__((ext_vector_type(4)));

__device__ __forceinline__ u16b f2bf(float f) {
    union { float f; u32 i; } v; v.f = f;
    u32 x = v.i; x += 0x7fffu + ((x >> 16) & 1u);
    return (u16b)(x >> 16);
}
__device__ __forceinline__ float bf2f(u16b u) {
    union { u32 i; float f; } v; v.i = (u32)u << 16; return v.f;
}

__global__ void sentinel_kernel(float* out, int n) {
    int i = blockIdx.x * 256 + threadIdx.x;
    if (i < n) out[i] = 999.0f;
}

// ---------- prep: f32 -> bf16 table -----------------------------------------
__global__ void __launch_bounds__(256)
cvt_bf16_kernel(const float4* __restrict__ in, ushort4* __restrict__ out, int n4) {
    int stride = gridDim.x * 256;
    for (int i = blockIdx.x * 256 + threadIdx.x; i < n4; i += stride) {
        float4 v = in[i];
        ushort4 o;
        o.x = f2bf(v.x); o.y = f2bf(v.y); o.z = f2bf(v.z); o.w = f2bf(v.w);
        out[i] = o;
    }
}

// ---------- CSR build (validated R13) ---------------------------------------
__global__ void __launch_bounds__(256)
bin_hist_kernel(const int* __restrict__ dst, int* __restrict__ binhist,
                int n, int shift) {
    __shared__ int lh[256];
    int tid = threadIdx.x;
    lh[tid] = 0;
    __syncthreads();
    int base = blockIdx.x * 4096;
    #pragma unroll
    for (int k = 0; k < 16; ++k) {
        int e = base + k * 256 + tid;
        if (e < n) atomicAdd(&lh[dst[e] >> shift], 1);
    }
    __syncthreads();
    if (lh[tid] > 0) atomicAdd(binhist + tid, lh[tid]);
}

__global__ void __launch_bounds__(256)
bin_scan_kernel(const int* __restrict__ binhist, int* __restrict__ start,
                int* __restrict__ cur_bin, int nbins) {
    __shared__ int sh[256];
    int t = threadIdx.x;
    int v = (t < nbins) ? binhist[t] : 0;
    sh[t] = v;
    __syncthreads();
    for (int off = 1; off < 256; off <<= 1) {
        int u = (t >= off) ? sh[t - off] : 0;
        __syncthreads();
        sh[t] += u;
        __syncthreads();
    }
    if (t < nbins) { start[t] = sh[t] - v; cur_bin[t] = sh[t] - v; }
    if (t == 255) start[nbins] = sh[255];
}

__global__ void __launch_bounds__(256)
bin_scatter_kernel(const int* __restrict__ src, const int* __restrict__ dst,
                   const int* __restrict__ remap,
                   int* __restrict__ cur_bin, u32* __restrict__ staging,
                   int n, int shift) {
    __shared__ int lh[256], sc[256], lrp[256], lcur[256], lbase[256];
    __shared__ u32 stage[4096];
    __shared__ u8  sbin[4096];
    int tid = threadIdx.x;
    lh[tid] = 0;
    __syncthreads();
    int base = blockIdx.x * 4096;
    int mybin[16]; u32 mypk[16];
    int dmask = (1 << shift) - 1;
    #pragma unroll
    for (int k = 0; k < 16; ++k) {
        int e = base + k * 256 + tid;
        mybin[k] = -1;
        if (e < n) {
            int d = dst[e];
            int s = src[e];
            if (remap) s = remap[s];
            int b = d >> shift;
            mybin[k] = b;
            mypk[k] = ((u32)(d & dmask) << 18) | (u32)s;
            atomicAdd(&lh[b], 1);
        }
    }
    __syncthreads();
    int v = lh[tid];
    sc[tid] = v;
    __syncthreads();
    for (int off = 1; off < 256; off <<= 1) {
        int u = (tid >= off) ? sc[tid - off] : 0;
        __syncthreads();
        sc[tid] += u;
        __syncthreads();
    }
    lrp[tid] = sc[tid] - v;
    lcur[tid] = sc[tid] - v;
    if (v > 0) lbase[tid] = atomicAdd(&cur_bin[tid], v);
    __syncthreads();
    #pragma unroll
    for (int k = 0; k < 16; ++k) {
        if (mybin[k] >= 0) {
            int p = atomicAdd(&lcur[mybin[k]], 1);
            stage[p] = mypk[k];
            sbin[p] = (u8)mybin[k];
        }
    }
    __syncthreads();
    int cnt_here = min(4096, n - base);
    for (int i = tid; i < cnt_here; i += 256) {
        int b = sbin[i];
        staging[lbase[b] + (i - lrp[b])] = stage[i];
    }
}

__global__ void __launch_bounds__(256)
bin_build_kernel(const u32* __restrict__ staging, const int* __restrict__ start,
                 int* __restrict__ bucket, int* __restrict__ rp,
                 int* __restrict__ cnt, int shift, int n_dst) {
    __shared__ int fh[1024], frp[1024], fcur[1024], part[256];
    int tid = threadIdx.x;
    int b = blockIdx.x;
    int s0 = start[b], s1 = start[b + 1];
    int m = s1 - s0;
    int nd = 1 << shift;
    int dbase = b << shift;
    for (int j = tid; j < nd; j += 256) fh[j] = 0;
    __syncthreads();
    for (int i = tid; i < m; i += 256)
        atomicAdd(&fh[staging[s0 + i] >> 18], 1);
    __syncthreads();
    int K = nd >> 8;
    int t0 = tid * K;
    int s = 0;
    for (int k = 0; k < K; ++k) s += fh[t0 + k];
    part[tid] = s;
    __syncthreads();
    for (int off = 1; off < 256; off <<= 1) {
        int u = (tid >= off) ? part[tid - off] : 0;
        __syncthreads();
        part[tid] += u;
        __syncthreads();
    }
    int run = part[tid] - s;
    for (int k = 0; k < K; ++k) {
        frp[t0 + k] = run; fcur[t0 + k] = run;
        run += fh[t0 + k];
    }
    __syncthreads();
    for (int j = tid; j < nd; j += 256) {
        int d = dbase + j;
        if (d < n_dst) { rp[d] = s0 + frp[j]; cnt[d] = fh[j]; }
    }
    for (int i = tid; i < m; i += 256) {
        u32 pk = staging[s0 + i];
        int dl = pk >> 18;
        int p = atomicAdd(&fcur[dl], 1);
        bucket[s0 + p] = (int)(pk & 0x3FFFFu);
    }
}

// ---------- gather-reduce: bf16 table in, bf16 agg out ----------------------
__global__ void __launch_bounds__(256)
gather_mean_bf16_kernel(const ushort4* __restrict__ x,    // rows = 16 x ushort4
                        const int* __restrict__ rp,
                        const int* __restrict__ cnt,
                        const int* __restrict__ bucket,
                        ushort4* __restrict__ agg,        // rows = 16 x ushort4
                        int n_dst)
{
    int wave = threadIdx.x >> 6, lane = threadIdx.x & 63;
    int i = blockIdx.x * 4 + wave;
    if (i >= n_dst) return;
    int st = rp[i], deg = cnt[i];
    int q = lane >> 4, c = lane & 15;
    float4 acc = make_float4(0.f, 0.f, 0.f, 0.f);
    for (int j = 0; j < deg; j += 4) {
        int idx = j + q;
        int r = bucket[st + min(idx, deg - 1)];
        float m = (idx < deg) ? 1.0f : 0.0f;
        ushort4 v = x[(size_t)r * 16 + c];
        acc.x += m * bf2f(v.x); acc.y += m * bf2f(v.y);
        acc.z += m * bf2f(v.z); acc.w += m * bf2f(v.w);
    }
    acc.x += __shfl_xor(acc.x, 16); acc.y += __shfl_xor(acc.y, 16);
    acc.z += __shfl_xor(acc.z, 16); acc.w += __shfl_xor(acc.w, 16);
    acc.x += __shfl_xor(acc.x, 32); acc.y += __shfl_xor(acc.y, 32);
    acc.z += __shfl_xor(acc.z, 32); acc.w += __shfl_xor(acc.w, 32);
    if (q == 0) {
        float inv = 1.0f / fmaxf((float)deg, 1.0f);
        ushort4 o;
        o.x = f2bf(acc.x * inv); o.y = f2bf(acc.y * inv);
        o.z = f2bf(acc.z * inv); o.w = f2bf(acc.w * inv);
        agg[(size_t)i * 16 + c] = o;
    }
}

// ---------- MFMA epilogues (R19 mapping, verified absmax 0.0156) ------------
// stage a bf16 row from a table into wa (u32 copy, 32 u32/row)
#define STAGE_ABF(DST, TBL, ROWID_EXPR)                                     \
    for (int idx = threadIdx.x; idx < 2048; idx += 256) {                   \
        int rr_ = idx >> 5, kk_ = idx & 31;                                 \
        ((u32*)&DST[rr_][0])[kk_] =                                         \
            ((const u32*)((TBL) + (size_t)(ROWID_EXPR) * 64))[kk_];         \
    }
// stage f32 rows -> bf16 LDS (R19)
#define STAGE_AF32(DST, SRCPTR_EXPR)                                        \
    for (int idx = threadIdx.x; idx < 4096; idx += 256) {                   \
        int r = idx >> 6, k = idx & 63;                                     \
        DST[r][k] = (short)f2bf((SRCPTR_EXPR)[k]);                          \
    }
#define STAGE_W1(DST, Wp)                                                   \
    for (int idx = threadIdx.x; idx < 4096; idx += 256) {                   \
        int j = idx >> 6, k = idx & 63;                                     \
        DST[j][k] = (short)f2bf((Wp)[idx]);                                 \
    }
#define STAGE_W2(DST, Wp, Wq)                                               \
    for (int idx = threadIdx.x; idx < 4096; idx += 256) {                   \
        int j = idx >> 6, k = idx & 63;                                     \
        DST[j][k] = (short)f2bf((Wp)[idx] + (Wq)[idx]);                     \
    }
#define MFMA_PHASE(ALDS, WLDS)                                              \
    _Pragma("unroll")                                                       \
    for (int kc = 0; kc < 2; ++kc) {                                        \
        short8 af = *(const short8*)&ALDS[lr0 + m][kc * 32 + kg * 8];       \
        _Pragma("unroll")                                                   \
        for (int nt = 0; nt < 4; ++nt) {                                    \
            short8 bf = *(const short8*)&WLDS[nt * 16 + m][kc * 32 + kg * 8];\
            acc[nt] = __builtin_amdgcn_mfma_f32_16x16x32_bf16(af, bf, acc[nt], 0, 0, 0); \
        }                                                                   \
    }

__global__ void __launch_bounds__(256)
epi_label_kernel(const u16b* __restrict__ agg_tl,    // bf16 tables
                 const u16b* __restrict__ agg_ll,
                 const u16b* __restrict__ lbf,       // bf16 label_emb
                 const int* __restrict__ nid,
                 const float* __restrict__ Wl_tl, const float* __restrict__ bl_tl,
                 const float* __restrict__ Wr_tl,
                 const float* __restrict__ Wl_ll, const float* __restrict__ bl_ll,
                 const float* __restrict__ Wr_ll,
                 float* __restrict__ out, int n)
{
    __shared__ short wa[64][72];
    __shared__ short w0[64][72];
    __shared__ short w1[64][72];
    __shared__ int   ndl[64];

    int tid = threadIdx.x;
    int base = blockIdx.x * 64;
    int lane = tid & 63;
    int m = lane & 15, kg = lane >> 4;
    int lr0 = (tid >> 6) * 16;

    if (tid < 64) ndl[tid] = nid[min(base + tid, n - 1)];
    STAGE_W1(w0, Wl_tl)
    STAGE_W1(w1, Wl_ll)
    STAGE_ABF(wa, agg_tl, min(base + rr_, n - 1))
    __syncthreads();

    f32x4 acc[4];
    #pragma unroll
    for (int nt = 0; nt < 4; ++nt) {
        float b = bl_tl[nt * 16 + m] + bl_ll[nt * 16 + m];
        acc[nt] = (f32x4){b, b, b, b};
    }

    MFMA_PHASE(wa, w0)               // agg_tl x Wl_tl^T
    __syncthreads();
    STAGE_ABF(wa, agg_ll, min(base + rr_, n - 1))
    __syncthreads();
    MFMA_PHASE(wa, w1)               // agg_ll x Wl_ll^T
    __syncthreads();
    STAGE_W2(w0, Wr_tl, Wr_ll)
    STAGE_ABF(wa, lbf, ndl[rr_])
    __syncthreads();
    MFMA_PHASE(wa, w0)               // x_label x (Wr_tl+Wr_ll)^T

    #pragma unroll
    for (int nt = 0; nt < 4; ++nt) {
        #pragma unroll
        for (int j = 0; j < 4; ++j) {
            int gi = base + lr0 + kg * 4 + j;
            if (gi < n)
                out[(size_t)gi * 64 + nt * 16 + m] = fmaxf(acc[nt][j], 0.0f);
        }
    }
}

__global__ void __launch_bounds__(256)
epi_title_kernel(const u16b* __restrict__ agg_lt,    // bf16
                 const float* __restrict__ title_x,  // f32 (sequential)
                 const float* __restrict__ Wl_tl, const float* __restrict__ bl_tl,
                 const float* __restrict__ Wr_tl,
                 float* __restrict__ out, int n)
{
    __shared__ short wa[64][72];
    __shared__ short w0[64][72];
    __shared__ short w1[64][72];

    int tid = threadIdx.x;
    int base = blockIdx.x * 64;
    int lane = tid & 63;
    int m = lane & 15, kg = lane >> 4;
    int lr0 = (tid >> 6) * 16;

    STAGE_W1(w0, Wl_tl)
    STAGE_W1(w1, Wr_tl)
    STAGE_ABF(wa, agg_lt, min(base + rr_, n - 1))
    __syncthreads();

    f32x4 acc[4];
    #pragma unroll
    for (int nt = 0; nt < 4; ++nt) {
        float b = bl_tl[nt * 16 + m];
        acc[nt] = (f32x4){b, b, b, b};
    }

    MFMA_PHASE(wa, w0)               // agg_lt x Wl_tl^T
    __syncthreads();
    STAGE_AF32(wa, title_x + (size_t)min(base + (idx >> 6), n - 1) * 64)
    __syncthreads();
    MFMA_PHASE(wa, w1)               // title_x x Wr_tl^T

    #pragma unroll
    for (int nt = 0; nt < 4; ++nt) {
        #pragma unroll
        for (int j = 0; j < 4; ++j) {
            int gi = base + lr0 + kg * 4 + j;
            if (gi < n)
                out[(size_t)gi * 64 + nt * 16 + m] = fmaxf(acc[nt][j], 0.0f);
        }
    }
}

extern "C" void kernel_launch(void* const* d_in, const int* in_sizes, int n_in,
                              void* d_out, int out_size, void* d_ws, size_t ws_size,
                              hipStream_t stream)
{
    const float* title_x   = (const float*)d_in[0];
    const float* label_emb = (const float*)d_in[1];
    const float* Wl_tl     = (const float*)d_in[2];
    const float* bl_tl     = (const float*)d_in[3];
    const float* Wr_tl     = (const float*)d_in[4];
    const float* Wl_ll     = (const float*)d_in[5];
    const float* bl_ll     = (const float*)d_in[6];
    const float* Wr_ll     = (const float*)d_in[7];
    const int* label_node_id = (const int*)d_in[8];
    const int* tl_src = (const int*)d_in[9];
    const int* tl_dst = (const int*)d_in[10];
    const int* lt_src = (const int*)d_in[11];
    const int* lt_dst = (const int*)d_in[12];
    const int* ll_src = (const int*)d_in[13];
    const int* ll_dst = (const int*)d_in[14];

    const int NT  = in_sizes[0] / 64;
    const int NL  = in_sizes[8];
    const int eTL = in_sizes[9];
    const int eLT = in_sizes[11];
    const int eLL = in_sizes[13];

    const int SH_L = 9,  NB_L = (NL + 511) >> 9;
    const int SH_T = 10, NB_T = (NT + 1023) >> 10;

    // ---- workspace layout ---------------------------------------------------
    // lbf (persistent) | A0: [tbf | agg_tl_bf | agg_ll_bf | rp/cnt x2 | bkts]
    //                    B overlays A0: [agg_lt_bf | rp/cnt | bkt_lt]
    // staging overlays the agg area of the current phase (dead before gathers).
    size_t szLbf  = (size_t)NL * 128;          // 12.8 MB
    size_t szTbf  = (size_t)NT * 128;          // 25.6 MB
    size_t szAgL  = (size_t)NL * 128;          // bf16 label agg
    size_t szAgT  = (size_t)NT * 128;          // bf16 title agg
    size_t iNL    = (size_t)NL * 4;
    size_t iNT    = (size_t)NT * 4;

    size_t regionA = szTbf + 2 * szAgL + 4 * iNL + ((size_t)eTL + eLL) * 4;
    size_t regionB = szAgT + 2 * iNT + (size_t)eLT * 4;
    size_t big     = regionA > regionB ? regionA : regionB;
    size_t szSmall = (256 + 257 + 256) * 4;
    size_t needed  = szLbf + big + szSmall;

    float* out_label = (float*)d_out;
    float* out_title = out_label + (size_t)NL * 64;

    if (ws_size < needed) {  // diagnosable: absmax ~999
        sentinel_kernel<<<(out_size + 255) / 256, 256, 0, stream>>>((float*)d_out, out_size);
        return;
    }

    char* base = (char*)d_ws;
    u16b* lbf = (u16b*)base;
    char* A0  = base + szLbf;
    // phase A
    u16b* tbf       = (u16b*)A0;
    u16b* agg_tl_bf = (u16b*)(A0 + szTbf);
    u16b* agg_ll_bf = (u16b*)(A0 + szTbf + szAgL);
    int* rp_tl  = (int*)(A0 + szTbf + 2 * szAgL);
    int* cnt_tl = rp_tl + NL;
    int* rp_ll  = cnt_tl + NL;
    int* cnt_ll = rp_ll + NL;
    int* bkt_tl = (int*)(A0 + szTbf + 2 * szAgL + 4 * iNL);
    int* bkt_ll = bkt_tl + eTL;
    u32* stagA  = (u32*)agg_tl_bf;             // dead before gathers
    // phase B (overlays A0; stream-ordered)
    u16b* agg_lt_bf = (u16b*)A0;
    int* rp_lt  = (int*)(A0 + szAgT);
    int* cnt_lt = rp_lt + NT;
    int* bkt_lt = (int*)(A0 + szAgT + 2 * iNT);
    u32* stagB  = (u32*)A0;                    // dead before gather_lt
    // small tail
    int* binhist = (int*)(base + szLbf + big);
    int* startb  = binhist + 256;
    int* curbin  = startb + 257;

    auto nchunk = [](int n) { return (n + 4095) / 4096; };

    auto build_csr = [&](const int* esrc, const int* edst, const int* remap,
                         u32* staging, int* bucket, int* rp, int* cnt,
                         int n_edges, int n_dst, int shift, int nbins) {
        (void)hipMemsetAsync(binhist, 0, nbins * 4, stream);
        bin_hist_kernel<<<nchunk(n_edges), 256, 0, stream>>>(edst, binhist, n_edges, shift);
        bin_scan_kernel<<<1, 256, 0, stream>>>(binhist, startb, curbin, nbins);
        bin_scatter_kernel<<<nchunk(n_edges), 256, 0, stream>>>(
            esrc, edst, remap, curbin, staging, n_edges, shift);
        bin_build_kernel<<<nbins, 256, 0, stream>>>(
            staging, startb, bucket, rp, cnt, shift, n_dst);
    };

    // ---- prep: bf16 tables --------------------------------------------------
    int n4t = NT * 16, n4l = NL * 16;
    cvt_bf16_kernel<<<2048, 256, 0, stream>>>((const float4*)title_x,   (ushort4*)tbf, n4t);
    cvt_bf16_kernel<<<2048, 256, 0, stream>>>((const float4*)label_emb, (ushort4*)lbf, n4l);

    // ---- phase A: label destination ----------------------------------------
    build_csr(tl_src, tl_dst, nullptr,       stagA, bkt_tl, rp_tl, cnt_tl, eTL, NL, SH_L, NB_L);
    build_csr(ll_src, ll_dst, label_node_id, stagA, bkt_ll, rp_ll, cnt_ll, eLL, NL, SH_L, NB_L);
    gather_mean_bf16_kernel<<<(NL + 3) / 4, 256, 0, stream>>>(
        (const ushort4*)tbf, rp_tl, cnt_tl, bkt_tl, (ushort4*)agg_tl_bf, NL);
    gather_mean_bf16_kernel<<<(NL + 3) / 4, 256, 0, stream>>>(
        (const ushort4*)lbf, rp_ll, cnt_ll, bkt_ll, (ushort4*)agg_ll_bf, NL);
    epi_label_kernel<<<(NL + 63) / 64, 256, 0, stream>>>(
        agg_tl_bf, agg_ll_bf, lbf, label_node_id,
        Wl_tl, bl_tl, Wr_tl, Wl_ll, bl_ll, Wr_ll, out_label, NL);

    // ---- phase B: title destination (stream-ordered reuse) -----------------
    build_csr(lt_src, lt_dst, label_node_id, stagB, bkt_lt, rp_lt, cnt_lt, eLT, NT, SH_T, NB_T);
    gather_mean_bf16_kernel<<<(NT + 3) / 4, 256, 0, stream>>>(
        (const ushort4*)lbf, rp_lt, cnt_lt, bkt_lt, (ushort4*)agg_lt_bf, NT);
    epi_title_kernel<<<(NT + 63) / 64, 256, 0, stream>>>(
        agg_lt_bf, title_x, Wl_tl, bl_tl, Wr_tl, out_title, NT);
}

// Round 21
// 386.391 us; speedup vs baseline: 1.0603x; 1.0603x over previous
//
#include <hip/hip_runtime.h>
#include <hip/hip_bf16.h>

// GNN_84043920048593: hetero SAGEConv. f32 I/O.
// R20 falsified "gather is byte-bound": halving bytes (bf16 tables) left time
// unchanged -> request-rate-bound (16 requests/row). R21: re-lane gather to
// 8 lanes x 16B per row (short8), 8 row-slots/wave -> 8 requests/row (2x
// fewer), double MLP. Everything else identical to R20.

typedef unsigned int u32;
typedef unsigned char u8;
typedef unsigned short u16b;
typedef short short8 __attribute__((ext_vector_type(8)));
typedef float f32x4 __attribute__((ext_vector_type(4)));

__device__ __forceinline__ u16b f2bf(float f) {
    union { float f; u32 i; } v; v.f = f;
    u32 x = v.i; x += 0x7fffu + ((x >> 16) & 1u);
    return (u16b)(x >> 16);
}
__device__ __forceinline__ float bf2f(u16b u) {
    union { u32 i; float f; } v; v.i = (u32)u << 16; return v.f;
}

__global__ void sentinel_kernel(float* out, int n) {
    int i = blockIdx.x * 256 + threadIdx.x;
    if (i < n) out[i] = 999.0f;
}

// ---------- prep: f32 -> bf16 table -----------------------------------------
__global__ void __launch_bounds__(256)
cvt_bf16_kernel(const float4* __restrict__ in, ushort4* __restrict__ out, int n4) {
    int stride = gridDim.x * 256;
    for (int i = blockIdx.x * 256 + threadIdx.x; i < n4; i += stride) {
        float4 v = in[i];
        ushort4 o;
        o.x = f2bf(v.x); o.y = f2bf(v.y); o.z = f2bf(v.z); o.w = f2bf(v.w);
        out[i] = o;
    }
}

// ---------- CSR build (validated R13) ---------------------------------------
__global__ void __launch_bounds__(256)
bin_hist_kernel(const int* __restrict__ dst, int* __restrict__ binhist,
                int n, int shift) {
    __shared__ int lh[256];
    int tid = threadIdx.x;
    lh[tid] = 0;
    __syncthreads();
    int base = blockIdx.x * 4096;
    #pragma unroll
    for (int k = 0; k < 16; ++k) {
        int e = base + k * 256 + tid;
        if (e < n) atomicAdd(&lh[dst[e] >> shift], 1);
    }
    __syncthreads();
    if (lh[tid] > 0) atomicAdd(binhist + tid, lh[tid]);
}

__global__ void __launch_bounds__(256)
bin_scan_kernel(const int* __restrict__ binhist, int* __restrict__ start,
                int* __restrict__ cur_bin, int nbins) {
    __shared__ int sh[256];
    int t = threadIdx.x;
    int v = (t < nbins) ? binhist[t] : 0;
    sh[t] = v;
    __syncthreads();
    for (int off = 1; off < 256; off <<= 1) {
        int u = (t >= off) ? sh[t - off] : 0;
        __syncthreads();
        sh[t] += u;
        __syncthreads();
    }
    if (t < nbins) { start[t] = sh[t] - v; cur_bin[t] = sh[t] - v; }
    if (t == 255) start[nbins] = sh[255];
}

__global__ void __launch_bounds__(256)
bin_scatter_kernel(const int* __restrict__ src, const int* __restrict__ dst,
                   const int* __restrict__ remap,
                   int* __restrict__ cur_bin, u32* __restrict__ staging,
                   int n, int shift) {
    __shared__ int lh[256], sc[256], lrp[256], lcur[256], lbase[256];
    __shared__ u32 stage[4096];
    __shared__ u8  sbin[4096];
    int tid = threadIdx.x;
    lh[tid] = 0;
    __syncthreads();
    int base = blockIdx.x * 4096;
    int mybin[16]; u32 mypk[16];
    int dmask = (1 << shift) - 1;
    #pragma unroll
    for (int k = 0; k < 16; ++k) {
        int e = base + k * 256 + tid;
        mybin[k] = -1;
        if (e < n) {
            int d = dst[e];
            int s = src[e];
            if (remap) s = remap[s];
            int b = d >> shift;
            mybin[k] = b;
            mypk[k] = ((u32)(d & dmask) << 18) | (u32)s;
            atomicAdd(&lh[b], 1);
        }
    }
    __syncthreads();
    int v = lh[tid];
    sc[tid] = v;
    __syncthreads();
    for (int off = 1; off < 256; off <<= 1) {
        int u = (tid >= off) ? sc[tid - off] : 0;
        __syncthreads();
        sc[tid] += u;
        __syncthreads();
    }
    lrp[tid] = sc[tid] - v;
    lcur[tid] = sc[tid] - v;
    if (v > 0) lbase[tid] = atomicAdd(&cur_bin[tid], v);
    __syncthreads();
    #pragma unroll
    for (int k = 0; k < 16; ++k) {
        if (mybin[k] >= 0) {
            int p = atomicAdd(&lcur[mybin[k]], 1);
            stage[p] = mypk[k];
            sbin[p] = (u8)mybin[k];
        }
    }
    __syncthreads();
    int cnt_here = min(4096, n - base);
    for (int i = tid; i < cnt_here; i += 256) {
        int b = sbin[i];
        staging[lbase[b] + (i - lrp[b])] = stage[i];
    }
}

__global__ void __launch_bounds__(256)
bin_build_kernel(const u32* __restrict__ staging, const int* __restrict__ start,
                 int* __restrict__ bucket, int* __restrict__ rp,
                 int* __restrict__ cnt, int shift, int n_dst) {
    __shared__ int fh[1024], frp[1024], fcur[1024], part[256];
    int tid = threadIdx.x;
    int b = blockIdx.x;
    int s0 = start[b], s1 = start[b + 1];
    int m = s1 - s0;
    int nd = 1 << shift;
    int dbase = b << shift;
    for (int j = tid; j < nd; j += 256) fh[j] = 0;
    __syncthreads();
    for (int i = tid; i < m; i += 256)
        atomicAdd(&fh[staging[s0 + i] >> 18], 1);
    __syncthreads();
    int K = nd >> 8;
    int t0 = tid * K;
    int s = 0;
    for (int k = 0; k < K; ++k) s += fh[t0 + k];
    part[tid] = s;
    __syncthreads();
    for (int off = 1; off < 256; off <<= 1) {
        int u = (tid >= off) ? part[tid - off] : 0;
        __syncthreads();
        part[tid] += u;
        __syncthreads();
    }
    int run = part[tid] - s;
    for (int k = 0; k < K; ++k) {
        frp[t0 + k] = run; fcur[t0 + k] = run;
        run += fh[t0 + k];
    }
    __syncthreads();
    for (int j = tid; j < nd; j += 256) {
        int d = dbase + j;
        if (d < n_dst) { rp[d] = s0 + frp[j]; cnt[d] = fh[j]; }
    }
    for (int i = tid; i < m; i += 256) {
        u32 pk = staging[s0 + i];
        int dl = pk >> 18;
        int p = atomicAdd(&fcur[dl], 1);
        bucket[s0 + p] = (int)(pk & 0x3FFFFu);
    }
}

// ---------- gather-reduce: 8 lanes x 16B per row, 8 row-slots/wave ----------
__global__ void __launch_bounds__(256)
gather_mean_bf16_kernel(const short8* __restrict__ x,     // rows = 8 x short8
                        const int* __restrict__ rp,
                        const int* __restrict__ cnt,
                        const int* __restrict__ bucket,
                        short8* __restrict__ agg,         // rows = 8 x short8
                        int n_dst)
{
    int wave = threadIdx.x >> 6, lane = threadIdx.x & 63;
    int i = blockIdx.x * 4 + wave;
    if (i >= n_dst) return;
    int st = rp[i], deg = cnt[i];
    int q = lane >> 3, c = lane & 7;     // 8 row-slots x 8 chunks of 16B
    float acc[8] = {0.f, 0.f, 0.f, 0.f, 0.f, 0.f, 0.f, 0.f};
    for (int j = 0; j < deg; j += 8) {
        int idx = j + q;
        int r = bucket[st + min(idx, deg - 1)];
        float m = (idx < deg) ? 1.0f : 0.0f;
        short8 v = x[(size_t)r * 8 + c];
        #pragma unroll
        for (int t = 0; t < 8; ++t) acc[t] += m * bf2f((u16b)v[t]);
    }
    // reduce across the 8 row slots (lane bits 3,4,5)
    #pragma unroll
    for (int off = 8; off <= 32; off <<= 1) {
        #pragma unroll
        for (int t = 0; t < 8; ++t) acc[t] += __shfl_xor(acc[t], off);
    }
    if (q == 0) {
        float inv = 1.0f / fmaxf((float)deg, 1.0f);
        short8 o;
        #pragma unroll
        for (int t = 0; t < 8; ++t) o[t] = (short)f2bf(acc[t] * inv);
        agg[(size_t)i * 8 + c] = o;
    }
}

// ---------- MFMA epilogues (R19 mapping, verified absmax 0.0156) ------------
#define STAGE_ABF(DST, TBL, ROWID_EXPR)                                     \
    for (int idx = threadIdx.x; idx < 2048; idx += 256) {                   \
        int rr_ = idx >> 5, kk_ = idx & 31;                                 \
        ((u32*)&DST[rr_][0])[kk_] =                                         \
            ((const u32*)((TBL) + (size_t)(ROWID_EXPR) * 64))[kk_];         \
    }
#define STAGE_AF32(DST, SRCPTR_EXPR)                                        \
    for (int idx = threadIdx.x; idx < 4096; idx += 256) {                   \
        int r = idx >> 6, k = idx & 63;                                     \
        DST[r][k] = (short)f2bf((SRCPTR_EXPR)[k]);                          \
    }
#define STAGE_W1(DST, Wp)                                                   \
    for (int idx = threadIdx.x; idx < 4096; idx += 256) {                   \
        int j = idx >> 6, k = idx & 63;                                     \
        DST[j][k] = (short)f2bf((Wp)[idx]);                                 \
    }
#define STAGE_W2(DST, Wp, Wq)                                               \
    for (int idx = threadIdx.x; idx < 4096; idx += 256) {                   \
        int j = idx >> 6, k = idx & 63;                                     \
        DST[j][k] = (short)f2bf((Wp)[idx] + (Wq)[idx]);                     \
    }
#define MFMA_PHASE(ALDS, WLDS)                                              \
    _Pragma("unroll")                                                       \
    for (int kc = 0; kc < 2; ++kc) {                                        \
        short8 af = *(const short8*)&ALDS[lr0 + m][kc * 32 + kg * 8];       \
        _Pragma("unroll")                                                   \
        for (int nt = 0; nt < 4; ++nt) {                                    \
            short8 bf = *(const short8*)&WLDS[nt * 16 + m][kc * 32 + kg * 8];\
            acc[nt] = __builtin_amdgcn_mfma_f32_16x16x32_bf16(af, bf, acc[nt], 0, 0, 0); \
        }                                                                   \
    }

__global__ void __launch_bounds__(256)
epi_label_kernel(const u16b* __restrict__ agg_tl,
                 const u16b* __restrict__ agg_ll,
                 const u16b* __restrict__ lbf,
                 const int* __restrict__ nid,
                 const float* __restrict__ Wl_tl, const float* __restrict__ bl_tl,
                 const float* __restrict__ Wr_tl,
                 const float* __restrict__ Wl_ll, const float* __restrict__ bl_ll,
                 const float* __restrict__ Wr_ll,
                 float* __restrict__ out, int n)
{
    __shared__ short wa[64][72];
    __shared__ short w0[64][72];
    __shared__ short w1[64][72];
    __shared__ int   ndl[64];

    int tid = threadIdx.x;
    int base = blockIdx.x * 64;
    int lane = tid & 63;
    int m = lane & 15, kg = lane >> 4;
    int lr0 = (tid >> 6) * 16;

    if (tid < 64) ndl[tid] = nid[min(base + tid, n - 1)];
    STAGE_W1(w0, Wl_tl)
    STAGE_W1(w1, Wl_ll)
    STAGE_ABF(wa, agg_tl, min(base + rr_, n - 1))
    __syncthreads();

    f32x4 acc[4];
    #pragma unroll
    for (int nt = 0; nt < 4; ++nt) {
        float b = bl_tl[nt * 16 + m] + bl_ll[nt * 16 + m];
        acc[nt] = (f32x4){b, b, b, b};
    }

    MFMA_PHASE(wa, w0)               // agg_tl x Wl_tl^T
    __syncthreads();
    STAGE_ABF(wa, agg_ll, min(base + rr_, n - 1))
    __syncthreads();
    MFMA_PHASE(wa, w1)               // agg_ll x Wl_ll^T
    __syncthreads();
    STAGE_W2(w0, Wr_tl, Wr_ll)
    STAGE_ABF(wa, lbf, ndl[rr_])
    __syncthreads();
    MFMA_PHASE(wa, w0)               // x_label x (Wr_tl+Wr_ll)^T

    #pragma unroll
    for (int nt = 0; nt < 4; ++nt) {
        #pragma unroll
        for (int j = 0; j < 4; ++j) {
            int gi = base + lr0 + kg * 4 + j;
            if (gi < n)
                out[(size_t)gi * 64 + nt * 16 + m] = fmaxf(acc[nt][j], 0.0f);
        }
    }
}

__global__ void __launch_bounds__(256)
epi_title_kernel(const u16b* __restrict__ agg_lt,
                 const float* __restrict__ title_x,
                 const float* __restrict__ Wl_tl, const float* __restrict__ bl_tl,
                 const float* __restrict__ Wr_tl,
                 float* __restrict__ out, int n)
{
    __shared__ short wa[64][72];
    __shared__ short w0[64][72];
    __shared__ short w1[64][72];

    int tid = threadIdx.x;
    int base = blockIdx.x * 64;
    int lane = tid & 63;
    int m = lane & 15, kg = lane >> 4;
    int lr0 = (tid >> 6) * 16;

    STAGE_W1(w0, Wl_tl)
    STAGE_W1(w1, Wr_tl)
    STAGE_ABF(wa, agg_lt, min(base + rr_, n - 1))
    __syncthreads();

    f32x4 acc[4];
    #pragma unroll
    for (int nt = 0; nt < 4; ++nt) {
        float b = bl_tl[nt * 16 + m];
        acc[nt] = (f32x4){b, b, b, b};
    }

    MFMA_PHASE(wa, w0)               // agg_lt x Wl_tl^T
    __syncthreads();
    STAGE_AF32(wa, title_x + (size_t)min(base + (idx >> 6), n - 1) * 64)
    __syncthreads();
    MFMA_PHASE(wa, w1)               // title_x x Wr_tl^T

    #pragma unroll
    for (int nt = 0; nt < 4; ++nt) {
        #pragma unroll
        for (int j = 0; j < 4; ++j) {
            int gi = base + lr0 + kg * 4 + j;
            if (gi < n)
                out[(size_t)gi * 64 + nt * 16 + m] = fmaxf(acc[nt][j], 0.0f);
        }
    }
}

extern "C" void kernel_launch(void* const* d_in, const int* in_sizes, int n_in,
                              void* d_out, int out_size, void* d_ws, size_t ws_size,
                              hipStream_t stream)
{
    const float* title_x   = (const float*)d_in[0];
    const float* label_emb = (const float*)d_in[1];
    const float* Wl_tl     = (const float*)d_in[2];
    const float* bl_tl     = (const float*)d_in[3];
    const float* Wr_tl     = (const float*)d_in[4];
    const float* Wl_ll     = (const float*)d_in[5];
    const float* bl_ll     = (const float*)d_in[6];
    const float* Wr_ll     = (const float*)d_in[7];
    const int* label_node_id = (const int*)d_in[8];
    const int* tl_src = (const int*)d_in[9];
    const int* tl_dst = (const int*)d_in[10];
    const int* lt_src = (const int*)d_in[11];
    const int* lt_dst = (const int*)d_in[12];
    const int* ll_src = (const int*)d_in[13];
    const int* ll_dst = (const int*)d_in[14];

    const int NT  = in_sizes[0] / 64;
    const int NL  = in_sizes[8];
    const int eTL = in_sizes[9];
    const int eLT = in_sizes[11];
    const int eLL = in_sizes[13];

    const int SH_L = 9,  NB_L = (NL + 511) >> 9;
    const int SH_T = 10, NB_T = (NT + 1023) >> 10;

    size_t szLbf  = (size_t)NL * 128;
    size_t szTbf  = (size_t)NT * 128;
    size_t szAgL  = (size_t)NL * 128;
    size_t szAgT  = (size_t)NT * 128;
    size_t iNL    = (size_t)NL * 4;
    size_t iNT    = (size_t)NT * 4;

    size_t regionA = szTbf + 2 * szAgL + 4 * iNL + ((size_t)eTL + eLL) * 4;
    size_t regionB = szAgT + 2 * iNT + (size_t)eLT * 4;
    size_t big     = regionA > regionB ? regionA : regionB;
    size_t szSmall = (256 + 257 + 256) * 4;
    size_t needed  = szLbf + big + szSmall;

    float* out_label = (float*)d_out;
    float* out_title = out_label + (size_t)NL * 64;

    if (ws_size < needed) {  // diagnosable: absmax ~999
        sentinel_kernel<<<(out_size + 255) / 256, 256, 0, stream>>>((float*)d_out, out_size);
        return;
    }

    char* base = (char*)d_ws;
    u16b* lbf = (u16b*)base;
    char* A0  = base + szLbf;
    u16b* tbf       = (u16b*)A0;
    u16b* agg_tl_bf = (u16b*)(A0 + szTbf);
    u16b* agg_ll_bf = (u16b*)(A0 + szTbf + szAgL);
    int* rp_tl  = (int*)(A0 + szTbf + 2 * szAgL);
    int* cnt_tl = rp_tl + NL;
    int* rp_ll  = cnt_tl + NL;
    int* cnt_ll = rp_ll + NL;
    int* bkt_tl = (int*)(A0 + szTbf + 2 * szAgL + 4 * iNL);
    int* bkt_ll = bkt_tl + eTL;
    u32* stagA  = (u32*)agg_tl_bf;
    u16b* agg_lt_bf = (u16b*)A0;
    int* rp_lt  = (int*)(A0 + szAgT);
    int* cnt_lt = rp_lt + NT;
    int* bkt_lt = (int*)(A0 + szAgT + 2 * iNT);
    u32* stagB  = (u32*)A0;
    int* binhist = (int*)(base + szLbf + big);
    int* startb  = binhist + 256;
    int* curbin  = startb + 257;

    auto nchunk = [](int n) { return (n + 4095) / 4096; };

    auto build_csr = [&](const int* esrc, const int* edst, const int* remap,
                         u32* staging, int* bucket, int* rp, int* cnt,
                         int n_edges, int n_dst, int shift, int nbins) {
        (void)hipMemsetAsync(binhist, 0, nbins * 4, stream);
        bin_hist_kernel<<<nchunk(n_edges), 256, 0, stream>>>(edst, binhist, n_edges, shift);
        bin_scan_kernel<<<1, 256, 0, stream>>>(binhist, startb, curbin, nbins);
        bin_scatter_kernel<<<nchunk(n_edges), 256, 0, stream>>>(
            esrc, edst, remap, curbin, staging, n_edges, shift);
        bin_build_kernel<<<nbins, 256, 0, stream>>>(
            staging, startb, bucket, rp, cnt, shift, n_dst);
    };

    // ---- prep: bf16 tables --------------------------------------------------
    int n4t = NT * 16, n4l = NL * 16;
    cvt_bf16_kernel<<<2048, 256, 0, stream>>>((const float4*)title_x,   (ushort4*)tbf, n4t);
    cvt_bf16_kernel<<<2048, 256, 0, stream>>>((const float4*)label_emb, (ushort4*)lbf, n4l);

    // ---- phase A: label destination ----------------------------------------
    build_csr(tl_src, tl_dst, nullptr,       stagA, bkt_tl, rp_tl, cnt_tl, eTL, NL, SH_L, NB_L);
    build_csr(ll_src, ll_dst, label_node_id, stagA, bkt_ll, rp_ll, cnt_ll, eLL, NL, SH_L, NB_L);
    gather_mean_bf16_kernel<<<(NL + 3) / 4, 256, 0, stream>>>(
        (const short8*)tbf, rp_tl, cnt_tl, bkt_tl, (short8*)agg_tl_bf, NL);
    gather_mean_bf16_kernel<<<(NL + 3) / 4, 256, 0, stream>>>(
        (const short8*)lbf, rp_ll, cnt_ll, bkt_ll, (short8*)agg_ll_bf, NL);
    epi_label_kernel<<<(NL + 63) / 64, 256, 0, stream>>>(
        agg_tl_bf, agg_ll_bf, lbf, label_node_id,
        Wl_tl, bl_tl, Wr_tl, Wl_ll, bl_ll, Wr_ll, out_label, NL);

    // ---- phase B: title destination (stream-ordered reuse) -----------------
    build_csr(lt_src, lt_dst, label_node_id, stagB, bkt_lt, rp_lt, cnt_lt, eLT, NT, SH_T, NB_T);
    gather_mean_bf16_kernel<<<(NT + 3) / 4, 256, 0, stream>>>(
        (const short8*)lbf, rp_lt, cnt_lt, bkt_lt, (short8*)agg_lt_bf, NT);
    epi_title_kernel<<<(NT + 63) / 64, 256, 0, stream>>>(
        agg_lt_bf, title_x, Wl_tl, bl_tl, Wr_tl, out_title, NT);
}

// Round 24
// 345.982 us; speedup vs baseline: 1.1841x; 1.1168x over previous
//
#include <hip/hip_runtime.h>
#include <hip/hip_bf16.h>

// GNN_84043920048593: hetero SAGEConv. f32 I/O.
// R21: 386us; gather 72us @ VALUBusy 59% — reduction-tree overhead (3 stages
// x 8 accs = 48 ops vs 16 payload ops at deg 8). R22: 2 nodes/wave, 4 row
// slots each half — 2-stage reduction, prologue amortized, requests same.

typedef unsigned int u32;
typedef unsigned char u8;
typedef unsigned short u16b;
typedef short short8 __attribute__((ext_vector_type(8)));
typedef float f32x4 __attribute__((ext_vector_type(4)));

__device__ __forceinline__ u16b f2bf(float f) {
    union { float f; u32 i; } v; v.f = f;
    u32 x = v.i; x += 0x7fffu + ((x >> 16) & 1u);
    return (u16b)(x >> 16);
}
__device__ __forceinline__ float bf2f(u16b u) {
    union { u32 i; float f; } v; v.i = (u32)u << 16; return v.f;
}

__global__ void sentinel_kernel(float* out, int n) {
    int i = blockIdx.x * 256 + threadIdx.x;
    if (i < n) out[i] = 999.0f;
}

// ---------- prep: f32 -> bf16 table -----------------------------------------
__global__ void __launch_bounds__(256)
cvt_bf16_kernel(const float4* __restrict__ in, ushort4* __restrict__ out, int n4) {
    int stride = gridDim.x * 256;
    for (int i = blockIdx.x * 256 + threadIdx.x; i < n4; i += stride) {
        float4 v = in[i];
        ushort4 o;
        o.x = f2bf(v.x); o.y = f2bf(v.y); o.z = f2bf(v.z); o.w = f2bf(v.w);
        out[i] = o;
    }
}

// ---------- CSR build (validated R13) ---------------------------------------
__global__ void __launch_bounds__(256)
bin_hist_kernel(const int* __restrict__ dst, int* __restrict__ binhist,
                int n, int shift) {
    __shared__ int lh[256];
    int tid = threadIdx.x;
    lh[tid] = 0;
    __syncthreads();
    int base = blockIdx.x * 4096;
    #pragma unroll
    for (int k = 0; k < 16; ++k) {
        int e = base + k * 256 + tid;
        if (e < n) atomicAdd(&lh[dst[e] >> shift], 1);
    }
    __syncthreads();
    if (lh[tid] > 0) atomicAdd(binhist + tid, lh[tid]);
}

__global__ void __launch_bounds__(256)
bin_scan_kernel(const int* __restrict__ binhist, int* __restrict__ start,
                int* __restrict__ cur_bin, int nbins) {
    __shared__ int sh[256];
    int t = threadIdx.x;
    int v = (t < nbins) ? binhist[t] : 0;
    sh[t] = v;
    __syncthreads();
    for (int off = 1; off < 256; off <<= 1) {
        int u = (t >= off) ? sh[t - off] : 0;
        __syncthreads();
        sh[t] += u;
        __syncthreads();
    }
    if (t < nbins) { start[t] = sh[t] - v; cur_bin[t] = sh[t] - v; }
    if (t == 255) start[nbins] = sh[255];
}

__global__ void __launch_bounds__(256)
bin_scatter_kernel(const int* __restrict__ src, const int* __restrict__ dst,
                   const int* __restrict__ remap,
                   int* __restrict__ cur_bin, u32* __restrict__ staging,
                   int n, int shift) {
    __shared__ int lh[256], sc[256], lrp[256], lcur[256], lbase[256];
    __shared__ u32 stage[4096];
    __shared__ u8  sbin[4096];
    int tid = threadIdx.x;
    lh[tid] = 0;
    __syncthreads();
    int base = blockIdx.x * 4096;
    int mybin[16]; u32 mypk[16];
    int dmask = (1 << shift) - 1;
    #pragma unroll
    for (int k = 0; k < 16; ++k) {
        int e = base + k * 256 + tid;
        mybin[k] = -1;
        if (e < n) {
            int d = dst[e];
            int s = src[e];
            if (remap) s = remap[s];
            int b = d >> shift;
            mybin[k] = b;
            mypk[k] = ((u32)(d & dmask) << 18) | (u32)s;
            atomicAdd(&lh[b], 1);
        }
    }
    __syncthreads();
    int v = lh[tid];
    sc[tid] = v;
    __syncthreads();
    for (int off = 1; off < 256; off <<= 1) {
        int u = (tid >= off) ? sc[tid - off] : 0;
        __syncthreads();
        sc[tid] += u;
        __syncthreads();
    }
    lrp[tid] = sc[tid] - v;
    lcur[tid] = sc[tid] - v;
    if (v > 0) lbase[tid] = atomicAdd(&cur_bin[tid], v);
    __syncthreads();
    #pragma unroll
    for (int k = 0; k < 16; ++k) {
        if (mybin[k] >= 0) {
            int p = atomicAdd(&lcur[mybin[k]], 1);
            stage[p] = mypk[k];
            sbin[p] = (u8)mybin[k];
        }
    }
    __syncthreads();
    int cnt_here = min(4096, n - base);
    for (int i = tid; i < cnt_here; i += 256) {
        int b = sbin[i];
        staging[lbase[b] + (i - lrp[b])] = stage[i];
    }
}

__global__ void __launch_bounds__(256)
bin_build_kernel(const u32* __restrict__ staging, const int* __restrict__ start,
                 int* __restrict__ bucket, int* __restrict__ rp,
                 int* __restrict__ cnt, int shift, int n_dst) {
    __shared__ int fh[1024], frp[1024], fcur[1024], part[256];
    int tid = threadIdx.x;
    int b = blockIdx.x;
    int s0 = start[b], s1 = start[b + 1];
    int m = s1 - s0;
    int nd = 1 << shift;
    int dbase = b << shift;
    for (int j = tid; j < nd; j += 256) fh[j] = 0;
    __syncthreads();
    for (int i = tid; i < m; i += 256)
        atomicAdd(&fh[staging[s0 + i] >> 18], 1);
    __syncthreads();
    int K = nd >> 8;
    int t0 = tid * K;
    int s = 0;
    for (int k = 0; k < K; ++k) s += fh[t0 + k];
    part[tid] = s;
    __syncthreads();
    for (int off = 1; off < 256; off <<= 1) {
        int u = (tid >= off) ? part[tid - off] : 0;
        __syncthreads();
        part[tid] += u;
        __syncthreads();
    }
    int run = part[tid] - s;
    for (int k = 0; k < K; ++k) {
        frp[t0 + k] = run; fcur[t0 + k] = run;
        run += fh[t0 + k];
    }
    __syncthreads();
    for (int j = tid; j < nd; j += 256) {
        int d = dbase + j;
        if (d < n_dst) { rp[d] = s0 + frp[j]; cnt[d] = fh[j]; }
    }
    for (int i = tid; i < m; i += 256) {
        u32 pk = staging[s0 + i];
        int dl = pk >> 18;
        int p = atomicAdd(&fcur[dl], 1);
        bucket[s0 + p] = (int)(pk & 0x3FFFFu);
    }
}

// ---------- gather-reduce: 2 nodes/wave, 4 row-slots x 8 chunks per half ----
__global__ void __launch_bounds__(256)
gather_mean_bf16_kernel(const short8* __restrict__ x,     // rows = 8 x short8
                        const int* __restrict__ rp,
                        const int* __restrict__ cnt,
                        const int* __restrict__ bucket,
                        short8* __restrict__ agg,         // rows = 8 x short8
                        int n_dst)
{
    int wave = threadIdx.x >> 6, lane = threadIdx.x & 63;
    int half = lane >> 5, hl = lane & 31;
    int q = hl >> 3, c = hl & 7;         // 4 row-slots x 8 chunks of 16B
    int i = blockIdx.x * 8 + wave * 2 + half;
    int ic = min(i, n_dst - 1);
    int st = rp[ic], deg = cnt[ic];
    float acc[8] = {0.f, 0.f, 0.f, 0.f, 0.f, 0.f, 0.f, 0.f};
    for (int j = 0; j < deg; j += 4) {
        int idx = j + q;
        int r = bucket[st + min(idx, deg - 1)];
        float m = (idx < deg) ? 1.0f : 0.0f;
        short8 v = x[(size_t)r * 8 + c];
        #pragma unroll
        for (int t = 0; t < 8; ++t) acc[t] += m * bf2f((u16b)v[t]);
    }
    // reduce across the 4 row slots (lane bits 3,4 — stays within the half)
    #pragma unroll
    for (int t = 0; t < 8; ++t) acc[t] += __shfl_xor(acc[t], 8);
    #pragma unroll
    for (int t = 0; t < 8; ++t) acc[t] += __shfl_xor(acc[t], 16);
    if (q == 0 && i < n_dst) {
        float inv = 1.0f / fmaxf((float)deg, 1.0f);
        short8 o;
        #pragma unroll
        for (int t = 0; t < 8; ++t) o[t] = (short)f2bf(acc[t] * inv);
        agg[(size_t)i * 8 + c] = o;
    }
}

// ---------- MFMA epilogues (R19 mapping, verified absmax 0.0156) ------------
#define STAGE_ABF(DST, TBL, ROWID_EXPR)                                     \
    for (int idx = threadIdx.x; idx < 2048; idx += 256) {                   \
        int rr_ = idx >> 5, kk_ = idx & 31;                                 \
        ((u32*)&DST[rr_][0])[kk_] =                                         \
            ((const u32*)((TBL) + (size_t)(ROWID_EXPR) * 64))[kk_];         \
    }
#define STAGE_AF32(DST, SRCPTR_EXPR)                                        \
    for (int idx = threadIdx.x; idx < 4096; idx += 256) {                   \
        int r = idx >> 6, k = idx & 63;                                     \
        DST[r][k] = (short)f2bf((SRCPTR_EXPR)[k]);                          \
    }
#define STAGE_W1(DST, Wp)                                                   \
    for (int idx = threadIdx.x; idx < 4096; idx += 256) {                   \
        int j = idx >> 6, k = idx & 63;                                     \
        DST[j][k] = (short)f2bf((Wp)[idx]);                                 \
    }
#define STAGE_W2(DST, Wp, Wq)                                               \
    for (int idx = threadIdx.x; idx < 4096; idx += 256) {                   \
        int j = idx >> 6, k = idx & 63;                                     \
        DST[j][k] = (short)f2bf((Wp)[idx] + (Wq)[idx]);                     \
    }
#define MFMA_PHASE(ALDS, WLDS)                                              \
    _Pragma("unroll")                                                       \
    for (int kc = 0; kc < 2; ++kc) {                                        \
        short8 af = *(const short8*)&ALDS[lr0 + m][kc * 32 + kg * 8];       \
        _Pragma("unroll")                                                   \
        for (int nt = 0; nt < 4; ++nt) {                                    \
            short8 bf = *(const short8*)&WLDS[nt * 16 + m][kc * 32 + kg * 8];\
            acc[nt] = __builtin_amdgcn_mfma_f32_16x16x32_bf16(af, bf, acc[nt], 0, 0, 0); \
        }                                                                   \
    }

__global__ void __launch_bounds__(256)
epi_label_kernel(const u16b* __restrict__ agg_tl,
                 const u16b* __restrict__ agg_ll,
                 const u16b* __restrict__ lbf,
                 const int* __restrict__ nid,
                 const float* __restrict__ Wl_tl, const float* __restrict__ bl_tl,
                 const float* __restrict__ Wr_tl,
                 const float* __restrict__ Wl_ll, const float* __restrict__ bl_ll,
                 const float* __restrict__ Wr_ll,
                 float* __restrict__ out, int n)
{
    __shared__ short wa[64][72];
    __shared__ short w0[64][72];
    __shared__ short w1[64][72];
    __shared__ int   ndl[64];

    int tid = threadIdx.x;
    int base = blockIdx.x * 64;
    int lane = tid & 63;
    int m = lane & 15, kg = lane >> 4;
    int lr0 = (tid >> 6) * 16;

    if (tid < 64) ndl[tid] = nid[min(base + tid, n - 1)];
    STAGE_W1(w0, Wl_tl)
    STAGE_W1(w1, Wl_ll)
    STAGE_ABF(wa, agg_tl, min(base + rr_, n - 1))
    __syncthreads();

    f32x4 acc[4];
    #pragma unroll
    for (int nt = 0; nt < 4; ++nt) {
        float b = bl_tl[nt * 16 + m] + bl_ll[nt * 16 + m];
        acc[nt] = (f32x4){b, b, b, b};
    }

    MFMA_PHASE(wa, w0)               // agg_tl x Wl_tl^T
    __syncthreads();
    STAGE_ABF(wa, agg_ll, min(base + rr_, n - 1))
    __syncthreads();
    MFMA_PHASE(wa, w1)               // agg_ll x Wl_ll^T
    __syncthreads();
    STAGE_W2(w0, Wr_tl, Wr_ll)
    STAGE_ABF(wa, lbf, ndl[rr_])
    __syncthreads();
    MFMA_PHASE(wa, w0)               // x_label x (Wr_tl+Wr_ll)^T

    #pragma unroll
    for (int nt = 0; nt < 4; ++nt) {
        #pragma unroll
        for (int j = 0; j < 4; ++j) {
            int gi = base + lr0 + kg * 4 + j;
            if (gi < n)
                out[(size_t)gi * 64 + nt * 16 + m] = fmaxf(acc[nt][j], 0.0f);
        }
    }
}

__global__ void __launch_bounds__(256)
epi_title_kernel(const u16b* __restrict__ agg_lt,
                 const float* __restrict__ title_x,
                 const float* __restrict__ Wl_tl, const float* __restrict__ bl_tl,
                 const float* __restrict__ Wr_tl,
                 float* __restrict__ out, int n)
{
    __shared__ short wa[64][72];
    __shared__ short w0[64][72];
    __shared__ short w1[64][72];

    int tid = threadIdx.x;
    int base = blockIdx.x * 64;
    int lane = tid & 63;
    int m = lane & 15, kg = lane >> 4;
    int lr0 = (tid >> 6) * 16;

    STAGE_W1(w0, Wl_tl)
    STAGE_W1(w1, Wr_tl)
    STAGE_ABF(wa, agg_lt, min(base + rr_, n - 1))
    __syncthreads();

    f32x4 acc[4];
    #pragma unroll
    for (int nt = 0; nt < 4; ++nt) {
        float b = bl_tl[nt * 16 + m];
        acc[nt] = (f32x4){b, b, b, b};
    }

    MFMA_PHASE(wa, w0)               // agg_lt x Wl_tl^T
    __syncthreads();
    STAGE_AF32(wa, title_x + (size_t)min(base + (idx >> 6), n - 1) * 64)
    __syncthreads();
    MFMA_PHASE(wa, w1)               // title_x x Wr_tl^T

    #pragma unroll
    for (int nt = 0; nt < 4; ++nt) {
        #pragma unroll
        for (int j = 0; j < 4; ++j) {
            int gi = base + lr0 + kg * 4 + j;
            if (gi < n)
                out[(size_t)gi * 64 + nt * 16 + m] = fmaxf(acc[nt][j], 0.0f);
        }
    }
}

extern "C" void kernel_launch(void* const* d_in, const int* in_sizes, int n_in,
                              void* d_out, int out_size, void* d_ws, size_t ws_size,
                              hipStream_t stream)
{
    const float* title_x   = (const float*)d_in[0];
    const float* label_emb = (const float*)d_in[1];
    const float* Wl_tl     = (const float*)d_in[2];
    const float* bl_tl     = (const float*)d_in[3];
    const float* Wr_tl     = (const float*)d_in[4];
    const float* Wl_ll     = (const float*)d_in[5];
    const float* bl_ll     = (const float*)d_in[6];
    const float* Wr_ll     = (const float*)d_in[7];
    const int* label_node_id = (const int*)d_in[8];
    const int* tl_src = (const int*)d_in[9];
    const int* tl_dst = (const int*)d_in[10];
    const int* lt_src = (const int*)d_in[11];
    const int* lt_dst = (const int*)d_in[12];
    const int* ll_src = (const int*)d_in[13];
    const int* ll_dst = (const int*)d_in[14];

    const int NT  = in_sizes[0] / 64;
    const int NL  = in_sizes[8];
    const int eTL = in_sizes[9];
    const int eLT = in_sizes[11];
    const int eLL = in_sizes[13];

    const int SH_L = 9,  NB_L = (NL + 511) >> 9;
    const int SH_T = 10, NB_T = (NT + 1023) >> 10;

    size_t szLbf  = (size_t)NL * 128;
    size_t szTbf  = (size_t)NT * 128;
    size_t szAgL  = (size_t)NL * 128;
    size_t szAgT  = (size_t)NT * 128;
    size_t iNL    = (size_t)NL * 4;
    size_t iNT    = (size_t)NT * 4;

    size_t regionA = szTbf + 2 * szAgL + 4 * iNL + ((size_t)eTL + eLL) * 4;
    size_t regionB = szAgT + 2 * iNT + (size_t)eLT * 4;
    size_t big     = regionA > regionB ? regionA : regionB;
    size_t szSmall = (256 + 257 + 256) * 4;
    size_t needed  = szLbf + big + szSmall;

    float* out_label = (float*)d_out;
    float* out_title = out_label + (size_t)NL * 64;

    if (ws_size < needed) {  // diagnosable: absmax ~999
        sentinel_kernel<<<(out_size + 255) / 256, 256, 0, stream>>>((float*)d_out, out_size);
        return;
    }

    char* base = (char*)d_ws;
    u16b* lbf = (u16b*)base;
    char* A0  = base + szLbf;
    u16b* tbf       = (u16b*)A0;
    u16b* agg_tl_bf = (u16b*)(A0 + szTbf);
    u16b* agg_ll_bf = (u16b*)(A0 + szTbf + szAgL);
    int* rp_tl  = (int*)(A0 + szTbf + 2 * szAgL);
    int* cnt_tl = rp_tl + NL;
    int* rp_ll  = cnt_tl + NL;
    int* cnt_ll = rp_ll + NL;
    int* bkt_tl = (int*)(A0 + szTbf + 2 * szAgL + 4 * iNL);
    int* bkt_ll = bkt_tl + eTL;
    u32* stagA  = (u32*)agg_tl_bf;
    u16b* agg_lt_bf = (u16b*)A0;
    int* rp_lt  = (int*)(A0 + szAgT);
    int* cnt_lt = rp_lt + NT;
    int* bkt_lt = (int*)(A0 + szAgT + 2 * iNT);
    u32* stagB  = (u32*)A0;
    int* binhist = (int*)(base + szLbf + big);
    int* startb  = binhist + 256;
    int* curbin  = startb + 257;

    auto nchunk = [](int n) { return (n + 4095) / 4096; };

    auto build_csr = [&](const int* esrc, const int* edst, const int* remap,
                         u32* staging, int* bucket, int* rp, int* cnt,
                         int n_edges, int n_dst, int shift, int nbins) {
        (void)hipMemsetAsync(binhist, 0, nbins * 4, stream);
        bin_hist_kernel<<<nchunk(n_edges), 256, 0, stream>>>(edst, binhist, n_edges, shift);
        bin_scan_kernel<<<1, 256, 0, stream>>>(binhist, startb, curbin, nbins);
        bin_scatter_kernel<<<nchunk(n_edges), 256, 0, stream>>>(
            esrc, edst, remap, curbin, staging, n_edges, shift);
        bin_build_kernel<<<nbins, 256, 0, stream>>>(
            staging, startb, bucket, rp, cnt, shift, n_dst);
    };

    // ---- prep: bf16 tables --------------------------------------------------
    int n4t = NT * 16, n4l = NL * 16;
    cvt_bf16_kernel<<<2048, 256, 0, stream>>>((const float4*)title_x,   (ushort4*)tbf, n4t);
    cvt_bf16_kernel<<<2048, 256, 0, stream>>>((const float4*)label_emb, (ushort4*)lbf, n4l);

    // ---- phase A: label destination ----------------------------------------
    build_csr(tl_src, tl_dst, nullptr,       stagA, bkt_tl, rp_tl, cnt_tl, eTL, NL, SH_L, NB_L);
    build_csr(ll_src, ll_dst, label_node_id, stagA, bkt_ll, rp_ll, cnt_ll, eLL, NL, SH_L, NB_L);
    gather_mean_bf16_kernel<<<(NL + 7) / 8, 256, 0, stream>>>(
        (const short8*)tbf, rp_tl, cnt_tl, bkt_tl, (short8*)agg_tl_bf, NL);
    gather_mean_bf16_kernel<<<(NL + 7) / 8, 256, 0, stream>>>(
        (const short8*)lbf, rp_ll, cnt_ll, bkt_ll, (short8*)agg_ll_bf, NL);
    epi_label_kernel<<<(NL + 63) / 64, 256, 0, stream>>>(
        agg_tl_bf, agg_ll_bf, lbf, label_node_id,
        Wl_tl, bl_tl, Wr_tl, Wl_ll, bl_ll, Wr_ll, out_label, NL);

    // ---- phase B: title destination (stream-ordered reuse) -----------------
    build_csr(lt_src, lt_dst, label_node_id, stagB, bkt_lt, rp_lt, cnt_lt, eLT, NT, SH_T, NB_T);
    gather_mean_bf16_kernel<<<(NT + 7) / 8, 256, 0, stream>>>(
        (const short8*)lbf, rp_lt, cnt_lt, bkt_lt, (short8*)agg_lt_bf, NT);
    epi_title_kernel<<<(NT + 63) / 64, 256, 0, stream>>>(
        agg_lt_bf, title_x, Wl_tl, bl_tl, Wr_tl, out_title, NT);
}

// Round 25
// 344.159 us; speedup vs baseline: 1.1904x; 1.0053x over previous
//
#include <hip/hip_runtime.h>
#include <hip/hip_bf16.h>

// GNN_84043920048593: hetero SAGEConv. f32 I/O.
// R24: 346us; gather 50us @ VALU 47% / HBM 28% — co-limited (cvt+fma floor +
// LLC request service). R25: gather tail-split (no clamp/mask in main loop)
// + merge the two label gathers into one dispatch. All else identical.

typedef unsigned int u32;
typedef unsigned char u8;
typedef unsigned short u16b;
typedef short short8 __attribute__((ext_vector_type(8)));
typedef float f32x4 __attribute__((ext_vector_type(4)));

__device__ __forceinline__ u16b f2bf(float f) {
    union { float f; u32 i; } v; v.f = f;
    u32 x = v.i; x += 0x7fffu + ((x >> 16) & 1u);
    return (u16b)(x >> 16);
}
__device__ __forceinline__ float bf2f(u16b u) {
    union { u32 i; float f; } v; v.i = (u32)u << 16; return v.f;
}

__global__ void sentinel_kernel(float* out, int n) {
    int i = blockIdx.x * 256 + threadIdx.x;
    if (i < n) out[i] = 999.0f;
}

// ---------- prep: f32 -> bf16 table -----------------------------------------
__global__ void __launch_bounds__(256)
cvt_bf16_kernel(const float4* __restrict__ in, ushort4* __restrict__ out, int n4) {
    int stride = gridDim.x * 256;
    for (int i = blockIdx.x * 256 + threadIdx.x; i < n4; i += stride) {
        float4 v = in[i];
        ushort4 o;
        o.x = f2bf(v.x); o.y = f2bf(v.y); o.z = f2bf(v.z); o.w = f2bf(v.w);
        out[i] = o;
    }
}

// ---------- CSR build (validated R13) ---------------------------------------
__global__ void __launch_bounds__(256)
bin_hist_kernel(const int* __restrict__ dst, int* __restrict__ binhist,
                int n, int shift) {
    __shared__ int lh[256];
    int tid = threadIdx.x;
    lh[tid] = 0;
    __syncthreads();
    int base = blockIdx.x * 4096;
    #pragma unroll
    for (int k = 0; k < 16; ++k) {
        int e = base + k * 256 + tid;
        if (e < n) atomicAdd(&lh[dst[e] >> shift], 1);
    }
    __syncthreads();
    if (lh[tid] > 0) atomicAdd(binhist + tid, lh[tid]);
}

__global__ void __launch_bounds__(256)
bin_scan_kernel(const int* __restrict__ binhist, int* __restrict__ start,
                int* __restrict__ cur_bin, int nbins) {
    __shared__ int sh[256];
    int t = threadIdx.x;
    int v = (t < nbins) ? binhist[t] : 0;
    sh[t] = v;
    __syncthreads();
    for (int off = 1; off < 256; off <<= 1) {
        int u = (t >= off) ? sh[t - off] : 0;
        __syncthreads();
        sh[t] += u;
        __syncthreads();
    }
    if (t < nbins) { start[t] = sh[t] - v; cur_bin[t] = sh[t] - v; }
    if (t == 255) start[nbins] = sh[255];
}

__global__ void __launch_bounds__(256)
bin_scatter_kernel(const int* __restrict__ src, const int* __restrict__ dst,
                   const int* __restrict__ remap,
                   int* __restrict__ cur_bin, u32* __restrict__ staging,
                   int n, int shift) {
    __shared__ int lh[256], sc[256], lrp[256], lcur[256], lbase[256];
    __shared__ u32 stage[4096];
    __shared__ u8  sbin[4096];
    int tid = threadIdx.x;
    lh[tid] = 0;
    __syncthreads();
    int base = blockIdx.x * 4096;
    int mybin[16]; u32 mypk[16];
    int dmask = (1 << shift) - 1;
    #pragma unroll
    for (int k = 0; k < 16; ++k) {
        int e = base + k * 256 + tid;
        mybin[k] = -1;
        if (e < n) {
            int d = dst[e];
            int s = src[e];
            if (remap) s = remap[s];
            int b = d >> shift;
            mybin[k] = b;
            mypk[k] = ((u32)(d & dmask) << 18) | (u32)s;
            atomicAdd(&lh[b], 1);
        }
    }
    __syncthreads();
    int v = lh[tid];
    sc[tid] = v;
    __syncthreads();
    for (int off = 1; off < 256; off <<= 1) {
        int u = (tid >= off) ? sc[tid - off] : 0;
        __syncthreads();
        sc[tid] += u;
        __syncthreads();
    }
    lrp[tid] = sc[tid] - v;
    lcur[tid] = sc[tid] - v;
    if (v > 0) lbase[tid] = atomicAdd(&cur_bin[tid], v);
    __syncthreads();
    #pragma unroll
    for (int k = 0; k < 16; ++k) {
        if (mybin[k] >= 0) {
            int p = atomicAdd(&lcur[mybin[k]], 1);
            stage[p] = mypk[k];
            sbin[p] = (u8)mybin[k];
        }
    }
    __syncthreads();
    int cnt_here = min(4096, n - base);
    for (int i = tid; i < cnt_here; i += 256) {
        int b = sbin[i];
        staging[lbase[b] + (i - lrp[b])] = stage[i];
    }
}

__global__ void __launch_bounds__(256)
bin_build_kernel(const u32* __restrict__ staging, const int* __restrict__ start,
                 int* __restrict__ bucket, int* __restrict__ rp,
                 int* __restrict__ cnt, int shift, int n_dst) {
    __shared__ int fh[1024], frp[1024], fcur[1024], part[256];
    int tid = threadIdx.x;
    int b = blockIdx.x;
    int s0 = start[b], s1 = start[b + 1];
    int m = s1 - s0;
    int nd = 1 << shift;
    int dbase = b << shift;
    for (int j = tid; j < nd; j += 256) fh[j] = 0;
    __syncthreads();
    for (int i = tid; i < m; i += 256)
        atomicAdd(&fh[staging[s0 + i] >> 18], 1);
    __syncthreads();
    int K = nd >> 8;
    int t0 = tid * K;
    int s = 0;
    for (int k = 0; k < K; ++k) s += fh[t0 + k];
    part[tid] = s;
    __syncthreads();
    for (int off = 1; off < 256; off <<= 1) {
        int u = (tid >= off) ? part[tid - off] : 0;
        __syncthreads();
        part[tid] += u;
        __syncthreads();
    }
    int run = part[tid] - s;
    for (int k = 0; k < K; ++k) {
        frp[t0 + k] = run; fcur[t0 + k] = run;
        run += fh[t0 + k];
    }
    __syncthreads();
    for (int j = tid; j < nd; j += 256) {
        int d = dbase + j;
        if (d < n_dst) { rp[d] = s0 + frp[j]; cnt[d] = fh[j]; }
    }
    for (int i = tid; i < m; i += 256) {
        u32 pk = staging[s0 + i];
        int dl = pk >> 18;
        int p = atomicAdd(&fcur[dl], 1);
        bucket[s0 + p] = (int)(pk & 0x3FFFFu);
    }
}

// ---------- gather-reduce body: 2 nodes/wave, 4 row-slots, tail-split -------
__device__ __forceinline__ void
gather_body(const short8* __restrict__ x, const int* __restrict__ rp,
            const int* __restrict__ cnt, const int* __restrict__ bucket,
            short8* __restrict__ agg, int n_dst, int blk)
{
    int wave = threadIdx.x >> 6, lane = threadIdx.x & 63;
    int half = lane >> 5, hl = lane & 31;
    int q = hl >> 3, c = hl & 7;         // 4 row-slots x 8 chunks of 16B
    int i = blk * 8 + wave * 2 + half;
    int ic = min(i, n_dst - 1);
    int st = rp[ic], deg = cnt[ic];
    float acc[8] = {0.f, 0.f, 0.f, 0.f, 0.f, 0.f, 0.f, 0.f};
    int j = 0;
    for (; j + 4 <= deg; j += 4) {       // full iterations: no clamp, no mask
        int r = bucket[st + j + q];
        short8 v = x[(size_t)r * 8 + c];
        #pragma unroll
        for (int t = 0; t < 8; ++t) acc[t] += bf2f((u16b)v[t]);
    }
    if (j + q < deg) {                   // tail (once, divergent)
        int r = bucket[st + j + q];
        short8 v = x[(size_t)r * 8 + c];
        #pragma unroll
        for (int t = 0; t < 8; ++t) acc[t] += bf2f((u16b)v[t]);
    }
    #pragma unroll
    for (int t = 0; t < 8; ++t) acc[t] += __shfl_xor(acc[t], 8);
    #pragma unroll
    for (int t = 0; t < 8; ++t) acc[t] += __shfl_xor(acc[t], 16);
    if (q == 0 && i < n_dst) {
        float inv = 1.0f / fmaxf((float)deg, 1.0f);
        short8 o;
        #pragma unroll
        for (int t = 0; t < 8; ++t) o[t] = (short)f2bf(acc[t] * inv);
        agg[(size_t)i * 8 + c] = o;
    }
}

__global__ void __launch_bounds__(256)
gather_mean_bf16_kernel(const short8* __restrict__ x,
                        const int* __restrict__ rp,
                        const int* __restrict__ cnt,
                        const int* __restrict__ bucket,
                        short8* __restrict__ agg,
                        int n_dst)
{
    gather_body(x, rp, cnt, bucket, agg, n_dst, blockIdx.x);
}

// merged label gathers: first na_blk blocks do (tl), rest do (ll)
__global__ void __launch_bounds__(256)
gather_mean_bf16_dual_kernel(const short8* __restrict__ xa,
                             const int* __restrict__ rpa, const int* __restrict__ cnta,
                             const int* __restrict__ bkta, short8* __restrict__ agga,
                             const short8* __restrict__ xb,
                             const int* __restrict__ rpb, const int* __restrict__ cntb,
                             const int* __restrict__ bktb, short8* __restrict__ aggb,
                             int n_dst, int na_blk)
{
    if ((int)blockIdx.x < na_blk)
        gather_body(xa, rpa, cnta, bkta, agga, n_dst, blockIdx.x);
    else
        gather_body(xb, rpb, cntb, bktb, aggb, n_dst, blockIdx.x - na_blk);
}

// ---------- MFMA epilogues (R19 mapping, verified absmax 0.0156) ------------
#define STAGE_ABF(DST, TBL, ROWID_EXPR)                                     \
    for (int idx = threadIdx.x; idx < 2048; idx += 256) {                   \
        int rr_ = idx >> 5, kk_ = idx & 31;                                 \
        ((u32*)&DST[rr_][0])[kk_] =                                         \
            ((const u32*)((TBL) + (size_t)(ROWID_EXPR) * 64))[kk_];         \
    }
#define STAGE_AF32(DST, SRCPTR_EXPR)                                        \
    for (int idx = threadIdx.x; idx < 4096; idx += 256) {                   \
        int r = idx >> 6, k = idx & 63;                                     \
        DST[r][k] = (short)f2bf((SRCPTR_EXPR)[k]);                          \
    }
#define STAGE_W1(DST, Wp)                                                   \
    for (int idx = threadIdx.x; idx < 4096; idx += 256) {                   \
        int j = idx >> 6, k = idx & 63;                                     \
        DST[j][k] = (short)f2bf((Wp)[idx]);                                 \
    }
#define STAGE_W2(DST, Wp, Wq)                                               \
    for (int idx = threadIdx.x; idx < 4096; idx += 256) {                   \
        int j = idx >> 6, k = idx & 63;                                     \
        DST[j][k] = (short)f2bf((Wp)[idx] + (Wq)[idx]);                     \
    }
#define MFMA_PHASE(ALDS, WLDS)                                              \
    _Pragma("unroll")                                                       \
    for (int kc = 0; kc < 2; ++kc) {                                        \
        short8 af = *(const short8*)&ALDS[lr0 + m][kc * 32 + kg * 8];       \
        _Pragma("unroll")                                                   \
        for (int nt = 0; nt < 4; ++nt) {                                    \
            short8 bf = *(const short8*)&WLDS[nt * 16 + m][kc * 32 + kg * 8];\
            acc[nt] = __builtin_amdgcn_mfma_f32_16x16x32_bf16(af, bf, acc[nt], 0, 0, 0); \
        }                                                                   \
    }

__global__ void __launch_bounds__(256)
epi_label_kernel(const u16b* __restrict__ agg_tl,
                 const u16b* __restrict__ agg_ll,
                 const u16b* __restrict__ lbf,
                 const int* __restrict__ nid,
                 const float* __restrict__ Wl_tl, const float* __restrict__ bl_tl,
                 const float* __restrict__ Wr_tl,
                 const float* __restrict__ Wl_ll, const float* __restrict__ bl_ll,
                 const float* __restrict__ Wr_ll,
                 float* __restrict__ out, int n)
{
    __shared__ short wa[64][72];
    __shared__ short w0[64][72];
    __shared__ short w1[64][72];
    __shared__ int   ndl[64];

    int tid = threadIdx.x;
    int base = blockIdx.x * 64;
    int lane = tid & 63;
    int m = lane & 15, kg = lane >> 4;
    int lr0 = (tid >> 6) * 16;

    if (tid < 64) ndl[tid] = nid[min(base + tid, n - 1)];
    STAGE_W1(w0, Wl_tl)
    STAGE_W1(w1, Wl_ll)
    STAGE_ABF(wa, agg_tl, min(base + rr_, n - 1))
    __syncthreads();

    f32x4 acc[4];
    #pragma unroll
    for (int nt = 0; nt < 4; ++nt) {
        float b = bl_tl[nt * 16 + m] + bl_ll[nt * 16 + m];
        acc[nt] = (f32x4){b, b, b, b};
    }

    MFMA_PHASE(wa, w0)               // agg_tl x Wl_tl^T
    __syncthreads();
    STAGE_ABF(wa, agg_ll, min(base + rr_, n - 1))
    __syncthreads();
    MFMA_PHASE(wa, w1)               // agg_ll x Wl_ll^T
    __syncthreads();
    STAGE_W2(w0, Wr_tl, Wr_ll)
    STAGE_ABF(wa, lbf, ndl[rr_])
    __syncthreads();
    MFMA_PHASE(wa, w0)               // x_label x (Wr_tl+Wr_ll)^T

    #pragma unroll
    for (int nt = 0; nt < 4; ++nt) {
        #pragma unroll
        for (int j = 0; j < 4; ++j) {
            int gi = base + lr0 + kg * 4 + j;
            if (gi < n)
                out[(size_t)gi * 64 + nt * 16 + m] = fmaxf(acc[nt][j], 0.0f);
        }
    }
}

__global__ void __launch_bounds__(256)
epi_title_kernel(const u16b* __restrict__ agg_lt,
                 const float* __restrict__ title_x,
                 const float* __restrict__ Wl_tl, const float* __restrict__ bl_tl,
                 const float* __restrict__ Wr_tl,
                 float* __restrict__ out, int n)
{
    __shared__ short wa[64][72];
    __shared__ short w0[64][72];
    __shared__ short w1[64][72];

    int tid = threadIdx.x;
    int base = blockIdx.x * 64;
    int lane = tid & 63;
    int m = lane & 15, kg = lane >> 4;
    int lr0 = (tid >> 6) * 16;

    STAGE_W1(w0, Wl_tl)
    STAGE_W1(w1, Wr_tl)
    STAGE_ABF(wa, agg_lt, min(base + rr_, n - 1))
    __syncthreads();

    f32x4 acc[4];
    #pragma unroll
    for (int nt = 0; nt < 4; ++nt) {
        float b = bl_tl[nt * 16 + m];
        acc[nt] = (f32x4){b, b, b, b};
    }

    MFMA_PHASE(wa, w0)               // agg_lt x Wl_tl^T
    __syncthreads();
    STAGE_AF32(wa, title_x + (size_t)min(base + (idx >> 6), n - 1) * 64)
    __syncthreads();
    MFMA_PHASE(wa, w1)               // title_x x Wr_tl^T

    #pragma unroll
    for (int nt = 0; nt < 4; ++nt) {
        #pragma unroll
        for (int j = 0; j < 4; ++j) {
            int gi = base + lr0 + kg * 4 + j;
            if (gi < n)
                out[(size_t)gi * 64 + nt * 16 + m] = fmaxf(acc[nt][j], 0.0f);
        }
    }
}

extern "C" void kernel_launch(void* const* d_in, const int* in_sizes, int n_in,
                              void* d_out, int out_size, void* d_ws, size_t ws_size,
                              hipStream_t stream)
{
    const float* title_x   = (const float*)d_in[0];
    const float* label_emb = (const float*)d_in[1];
    const float* Wl_tl     = (const float*)d_in[2];
    const float* bl_tl     = (const float*)d_in[3];
    const float* Wr_tl     = (const float*)d_in[4];
    const float* Wl_ll     = (const float*)d_in[5];
    const float* bl_ll     = (const float*)d_in[6];
    const float* Wr_ll     = (const float*)d_in[7];
    const int* label_node_id = (const int*)d_in[8];
    const int* tl_src = (const int*)d_in[9];
    const int* tl_dst = (const int*)d_in[10];
    const int* lt_src = (const int*)d_in[11];
    const int* lt_dst = (const int*)d_in[12];
    const int* ll_src = (const int*)d_in[13];
    const int* ll_dst = (const int*)d_in[14];

    const int NT  = in_sizes[0] / 64;
    const int NL  = in_sizes[8];
    const int eTL = in_sizes[9];
    const int eLT = in_sizes[11];
    const int eLL = in_sizes[13];

    const int SH_L = 9,  NB_L = (NL + 511) >> 9;
    const int SH_T = 10, NB_T = (NT + 1023) >> 10;

    size_t szLbf  = (size_t)NL * 128;
    size_t szTbf  = (size_t)NT * 128;
    size_t szAgL  = (size_t)NL * 128;
    size_t szAgT  = (size_t)NT * 128;
    size_t iNL    = (size_t)NL * 4;
    size_t iNT    = (size_t)NT * 4;

    size_t regionA = szTbf + 2 * szAgL + 4 * iNL + ((size_t)eTL + eLL) * 4;
    size_t regionB = szAgT + 2 * iNT + (size_t)eLT * 4;
    size_t big     = regionA > regionB ? regionA : regionB;
    size_t szSmall = (256 + 257 + 256) * 4;
    size_t needed  = szLbf + big + szSmall;

    float* out_label = (float*)d_out;
    float* out_title = out_label + (size_t)NL * 64;

    if (ws_size < needed) {  // diagnosable: absmax ~999
        sentinel_kernel<<<(out_size + 255) / 256, 256, 0, stream>>>((float*)d_out, out_size);
        return;
    }

    char* base = (char*)d_ws;
    u16b* lbf = (u16b*)base;
    char* A0  = base + szLbf;
    u16b* tbf       = (u16b*)A0;
    u16b* agg_tl_bf = (u16b*)(A0 + szTbf);
    u16b* agg_ll_bf = (u16b*)(A0 + szTbf + szAgL);
    int* rp_tl  = (int*)(A0 + szTbf + 2 * szAgL);
    int* cnt_tl = rp_tl + NL;
    int* rp_ll  = cnt_tl + NL;
    int* cnt_ll = rp_ll + NL;
    int* bkt_tl = (int*)(A0 + szTbf + 2 * szAgL + 4 * iNL);
    int* bkt_ll = bkt_tl + eTL;
    u32* stagA  = (u32*)agg_tl_bf;
    u16b* agg_lt_bf = (u16b*)A0;
    int* rp_lt  = (int*)(A0 + szAgT);
    int* cnt_lt = rp_lt + NT;
    int* bkt_lt = (int*)(A0 + szAgT + 2 * iNT);
    u32* stagB  = (u32*)A0;
    int* binhist = (int*)(base + szLbf + big);
    int* startb  = binhist + 256;
    int* curbin  = startb + 257;

    auto nchunk = [](int n) { return (n + 4095) / 4096; };

    auto build_csr = [&](const int* esrc, const int* edst, const int* remap,
                         u32* staging, int* bucket, int* rp, int* cnt,
                         int n_edges, int n_dst, int shift, int nbins) {
        (void)hipMemsetAsync(binhist, 0, nbins * 4, stream);
        bin_hist_kernel<<<nchunk(n_edges), 256, 0, stream>>>(edst, binhist, n_edges, shift);
        bin_scan_kernel<<<1, 256, 0, stream>>>(binhist, startb, curbin, nbins);
        bin_scatter_kernel<<<nchunk(n_edges), 256, 0, stream>>>(
            esrc, edst, remap, curbin, staging, n_edges, shift);
        bin_build_kernel<<<nbins, 256, 0, stream>>>(
            staging, startb, bucket, rp, cnt, shift, n_dst);
    };

    // ---- prep: bf16 tables --------------------------------------------------
    int n4t = NT * 16, n4l = NL * 16;
    cvt_bf16_kernel<<<2048, 256, 0, stream>>>((const float4*)title_x,   (ushort4*)tbf, n4t);
    cvt_bf16_kernel<<<2048, 256, 0, stream>>>((const float4*)label_emb, (ushort4*)lbf, n4l);

    // ---- phase A: label destination ----------------------------------------
    build_csr(tl_src, tl_dst, nullptr,       stagA, bkt_tl, rp_tl, cnt_tl, eTL, NL, SH_L, NB_L);
    build_csr(ll_src, ll_dst, label_node_id, stagA, bkt_ll, rp_ll, cnt_ll, eLL, NL, SH_L, NB_L);
    int nblkL = (NL + 7) / 8;
    gather_mean_bf16_dual_kernel<<<2 * nblkL, 256, 0, stream>>>(
        (const short8*)tbf, rp_tl, cnt_tl, bkt_tl, (short8*)agg_tl_bf,
        (const short8*)lbf, rp_ll, cnt_ll, bkt_ll, (short8*)agg_ll_bf,
        NL, nblkL);
    epi_label_kernel<<<(NL + 63) / 64, 256, 0, stream>>>(
        agg_tl_bf, agg_ll_bf, lbf, label_node_id,
        Wl_tl, bl_tl, Wr_tl, Wl_ll, bl_ll, Wr_ll, out_label, NL);

    // ---- phase B: title destination (stream-ordered reuse) -----------------
    build_csr(lt_src, lt_dst, label_node_id, stagB, bkt_lt, rp_lt, cnt_lt, eLT, NT, SH_T, NB_T);
    gather_mean_bf16_kernel<<<(NT + 7) / 8, 256, 0, stream>>>(
        (const short8*)lbf, rp_lt, cnt_lt, bkt_lt, (short8*)agg_lt_bf, NT);
    epi_title_kernel<<<(NT + 63) / 64, 256, 0, stream>>>(
        agg_lt_bf, title_x, Wl_tl, bl_tl, Wr_tl, out_title, NT);
}

// Round 26
// 306.443 us; speedup vs baseline: 1.3369x; 1.1231x over previous
//
#include <hip/hip_runtime.h>
#include <hip/hip_bf16.h>

// GNN_84043920048593: hetero SAGEConv. f32 I/O.
// R25: 344us. Gathers at random-access co-limit (VALU 46% / 2.7TB/s random
// service); epis at MFMA+traffic floor. R26: collapse phase-A CSR build to
// 4 dispatches (grid-split dual kernels, bodies unchanged) + merged prep cvt.
// Removes ~5 stream drains.

typedef unsigned int u32;
typedef unsigned char u8;
typedef unsigned short u16b;
typedef short short8 __attribute__((ext_vector_type(8)));
typedef float f32x4 __attribute__((ext_vector_type(4)));

__device__ __forceinline__ u16b f2bf(float f) {
    union { float f; u32 i; } v; v.f = f;
    u32 x = v.i; x += 0x7fffu + ((x >> 16) & 1u);
    return (u16b)(x >> 16);
}
__device__ __forceinline__ float bf2f(u16b u) {
    union { u32 i; float f; } v; v.i = (u32)u << 16; return v.f;
}

__global__ void sentinel_kernel(float* out, int n) {
    int i = blockIdx.x * 256 + threadIdx.x;
    if (i < n) out[i] = 999.0f;
}

// ---------- prep: f32 -> bf16 tables (both in one dispatch) -----------------
__device__ __forceinline__ void cvt_body(const float4* in, ushort4* out,
                                         int n4, int blk, int nblk) {
    int stride = nblk * 256;
    for (int i = blk * 256 + (int)threadIdx.x; i < n4; i += stride) {
        float4 v = in[i];
        ushort4 o;
        o.x = f2bf(v.x); o.y = f2bf(v.y); o.z = f2bf(v.z); o.w = f2bf(v.w);
        out[i] = o;
    }
}
__global__ void __launch_bounds__(256)
cvt_bf16_dual_kernel(const float4* __restrict__ inA, ushort4* __restrict__ outA,
                     int n4A, int nblkA,
                     const float4* __restrict__ inB, ushort4* __restrict__ outB,
                     int n4B, int nblkB)
{
    if ((int)blockIdx.x < nblkA) cvt_body(inA, outA, n4A, blockIdx.x, nblkA);
    else                         cvt_body(inB, outB, n4B, blockIdx.x - nblkA, nblkB);
}

// ---------- CSR build bodies (logic identical to validated R13) -------------
__device__ __forceinline__ void hist_body(const int* __restrict__ dst,
                                          int* __restrict__ binhist,
                                          int n, int shift, int blk) {
    __shared__ int lh[256];
    int tid = threadIdx.x;
    lh[tid] = 0;
    __syncthreads();
    int base = blk * 4096;
    #pragma unroll
    for (int k = 0; k < 16; ++k) {
        int e = base + k * 256 + tid;
        if (e < n) atomicAdd(&lh[dst[e] >> shift], 1);
    }
    __syncthreads();
    if (lh[tid] > 0) atomicAdd(binhist + tid, lh[tid]);
}

__device__ __forceinline__ void scan_body(const int* __restrict__ binhist,
                                          int* __restrict__ start,
                                          int* __restrict__ cur_bin, int nbins) {
    __shared__ int sh[256];
    int t = threadIdx.x;
    int v = (t < nbins) ? binhist[t] : 0;
    sh[t] = v;
    __syncthreads();
    for (int off = 1; off < 256; off <<= 1) {
        int u = (t >= off) ? sh[t - off] : 0;
        __syncthreads();
        sh[t] += u;
        __syncthreads();
    }
    if (t < nbins) { start[t] = sh[t] - v; cur_bin[t] = sh[t] - v; }
    if (t == 255) start[nbins] = sh[255];
}

__device__ __forceinline__ void scatter_body(const int* __restrict__ src,
                                             const int* __restrict__ dst,
                                             const int* __restrict__ remap,
                                             int* __restrict__ cur_bin,
                                             u32* __restrict__ staging,
                                             int n, int shift, int blk) {
    __shared__ int lh[256], sc[256], lrp[256], lcur[256], lbase[256];
    __shared__ u32 stage[4096];
    __shared__ u8  sbin[4096];
    int tid = threadIdx.x;
    lh[tid] = 0;
    __syncthreads();
    int base = blk * 4096;
    int mybin[16]; u32 mypk[16];
    int dmask = (1 << shift) - 1;
    #pragma unroll
    for (int k = 0; k < 16; ++k) {
        int e = base + k * 256 + tid;
        mybin[k] = -1;
        if (e < n) {
            int d = dst[e];
            int s = src[e];
            if (remap) s = remap[s];
            int b = d >> shift;
            mybin[k] = b;
            mypk[k] = ((u32)(d & dmask) << 18) | (u32)s;
            atomicAdd(&lh[b], 1);
        }
    }
    __syncthreads();
    int v = lh[tid];
    sc[tid] = v;
    __syncthreads();
    for (int off = 1; off < 256; off <<= 1) {
        int u = (tid >= off) ? sc[tid - off] : 0;
        __syncthreads();
        sc[tid] += u;
        __syncthreads();
    }
    lrp[tid] = sc[tid] - v;
    lcur[tid] = sc[tid] - v;
    if (v > 0) lbase[tid] = atomicAdd(&cur_bin[tid], v);
    __syncthreads();
    #pragma unroll
    for (int k = 0; k < 16; ++k) {
        if (mybin[k] >= 0) {
            int p = atomicAdd(&lcur[mybin[k]], 1);
            stage[p] = mypk[k];
            sbin[p] = (u8)mybin[k];
        }
    }
    __syncthreads();
    int cnt_here = min(4096, n - base);
    for (int i = tid; i < cnt_here; i += 256) {
        int b = sbin[i];
        staging[lbase[b] + (i - lrp[b])] = stage[i];
    }
}

__device__ __forceinline__ void build_body(const u32* __restrict__ staging,
                                           const int* __restrict__ start,
                                           int* __restrict__ bucket,
                                           int* __restrict__ rp,
                                           int* __restrict__ cnt,
                                           int shift, int n_dst, int b) {
    __shared__ int fh[1024], frp[1024], fcur[1024], part[256];
    int tid = threadIdx.x;
    int s0 = start[b], s1 = start[b + 1];
    int m = s1 - s0;
    int nd = 1 << shift;
    int dbase = b << shift;
    for (int j = tid; j < nd; j += 256) fh[j] = 0;
    __syncthreads();
    for (int i = tid; i < m; i += 256)
        atomicAdd(&fh[staging[s0 + i] >> 18], 1);
    __syncthreads();
    int K = nd >> 8;
    int t0 = tid * K;
    int s = 0;
    for (int k = 0; k < K; ++k) s += fh[t0 + k];
    part[tid] = s;
    __syncthreads();
    for (int off = 1; off < 256; off <<= 1) {
        int u = (tid >= off) ? part[tid - off] : 0;
        __syncthreads();
        part[tid] += u;
        __syncthreads();
    }
    int run = part[tid] - s;
    for (int k = 0; k < K; ++k) {
        frp[t0 + k] = run; fcur[t0 + k] = run;
        run += fh[t0 + k];
    }
    __syncthreads();
    for (int j = tid; j < nd; j += 256) {
        int d = dbase + j;
        if (d < n_dst) { rp[d] = s0 + frp[j]; cnt[d] = fh[j]; }
    }
    for (int i = tid; i < m; i += 256) {
        u32 pk = staging[s0 + i];
        int dl = pk >> 18;
        int p = atomicAdd(&fcur[dl], 1);
        bucket[s0 + p] = (int)(pk & 0x3FFFFu);
    }
}

// ---------- single-type CSR kernels (phase B) -------------------------------
__global__ void __launch_bounds__(256)
bin_hist_kernel(const int* __restrict__ dst, int* __restrict__ binhist,
                int n, int shift) {
    hist_body(dst, binhist, n, shift, blockIdx.x);
}
__global__ void __launch_bounds__(256)
bin_scan_kernel(const int* __restrict__ binhist, int* __restrict__ start,
                int* __restrict__ cur_bin, int nbins) {
    scan_body(binhist, start, cur_bin, nbins);
}
__global__ void __launch_bounds__(256)
bin_scatter_kernel(const int* __restrict__ src, const int* __restrict__ dst,
                   const int* __restrict__ remap,
                   int* __restrict__ cur_bin, u32* __restrict__ staging,
                   int n, int shift) {
    scatter_body(src, dst, remap, cur_bin, staging, n, shift, blockIdx.x);
}
__global__ void __launch_bounds__(256)
bin_build_kernel(const u32* __restrict__ staging, const int* __restrict__ start,
                 int* __restrict__ bucket, int* __restrict__ rp,
                 int* __restrict__ cnt, int shift, int n_dst) {
    build_body(staging, start, bucket, rp, cnt, shift, n_dst, blockIdx.x);
}

// ---------- dual CSR kernels (phase A: tl + ll in one dispatch) -------------
__global__ void __launch_bounds__(256)
bin_hist_dual_kernel(const int* __restrict__ dstA, int* __restrict__ bhA, int nA, int nchA,
                     const int* __restrict__ dstB, int* __restrict__ bhB, int nB,
                     int shift) {
    if ((int)blockIdx.x < nchA) hist_body(dstA, bhA, nA, shift, blockIdx.x);
    else                        hist_body(dstB, bhB, nB, shift, blockIdx.x - nchA);
}
__global__ void __launch_bounds__(256)
bin_scan_dual_kernel(const int* __restrict__ bhA, int* __restrict__ stA, int* __restrict__ cuA,
                     const int* __restrict__ bhB, int* __restrict__ stB, int* __restrict__ cuB,
                     int nbins) {
    if (blockIdx.x == 0) scan_body(bhA, stA, cuA, nbins);
    else                 scan_body(bhB, stB, cuB, nbins);
}
__global__ void __launch_bounds__(256)
bin_scatter_dual_kernel(const int* __restrict__ srcA, const int* __restrict__ dstA,
                        int* __restrict__ cuA, u32* __restrict__ stgA, int nA, int nchA,
                        const int* __restrict__ srcB, const int* __restrict__ dstB,
                        const int* __restrict__ remapB,
                        int* __restrict__ cuB, u32* __restrict__ stgB, int nB,
                        int shift) {
    if ((int)blockIdx.x < nchA)
        scatter_body(srcA, dstA, nullptr, cuA, stgA, nA, shift, blockIdx.x);
    else
        scatter_body(srcB, dstB, remapB, cuB, stgB, nB, shift, blockIdx.x - nchA);
}
__global__ void __launch_bounds__(256)
bin_build_dual_kernel(const u32* __restrict__ stgA, const int* __restrict__ stA,
                      int* __restrict__ bkA, int* __restrict__ rpA, int* __restrict__ cnA,
                      const u32* __restrict__ stgB, const int* __restrict__ stB,
                      int* __restrict__ bkB, int* __restrict__ rpB, int* __restrict__ cnB,
                      int shift, int n_dst, int nbins) {
    if ((int)blockIdx.x < nbins)
        build_body(stgA, stA, bkA, rpA, cnA, shift, n_dst, blockIdx.x);
    else
        build_body(stgB, stB, bkB, rpB, cnB, shift, n_dst, blockIdx.x - nbins);
}

// ---------- gather-reduce (R24/R25 validated) -------------------------------
__device__ __forceinline__ void
gather_body(const short8* __restrict__ x, const int* __restrict__ rp,
            const int* __restrict__ cnt, const int* __restrict__ bucket,
            short8* __restrict__ agg, int n_dst, int blk)
{
    int wave = threadIdx.x >> 6, lane = threadIdx.x & 63;
    int half = lane >> 5, hl = lane & 31;
    int q = hl >> 3, c = hl & 7;
    int i = blk * 8 + wave * 2 + half;
    int ic = min(i, n_dst - 1);
    int st = rp[ic], deg = cnt[ic];
    float acc[8] = {0.f, 0.f, 0.f, 0.f, 0.f, 0.f, 0.f, 0.f};
    int j = 0;
    for (; j + 4 <= deg; j += 4) {
        int r = bucket[st + j + q];
        short8 v = x[(size_t)r * 8 + c];
        #pragma unroll
        for (int t = 0; t < 8; ++t) acc[t] += bf2f((u16b)v[t]);
    }
    if (j + q < deg) {
        int r = bucket[st + j + q];
        short8 v = x[(size_t)r * 8 + c];
        #pragma unroll
        for (int t = 0; t < 8; ++t) acc[t] += bf2f((u16b)v[t]);
    }
    #pragma unroll
    for (int t = 0; t < 8; ++t) acc[t] += __shfl_xor(acc[t], 8);
    #pragma unroll
    for (int t = 0; t < 8; ++t) acc[t] += __shfl_xor(acc[t], 16);
    if (q == 0 && i < n_dst) {
        float inv = 1.0f / fmaxf((float)deg, 1.0f);
        short8 o;
        #pragma unroll
        for (int t = 0; t < 8; ++t) o[t] = (short)f2bf(acc[t] * inv);
        agg[(size_t)i * 8 + c] = o;
    }
}

__global__ void __launch_bounds__(256)
gather_mean_bf16_kernel(const short8* __restrict__ x,
                        const int* __restrict__ rp,
                        const int* __restrict__ cnt,
                        const int* __restrict__ bucket,
                        short8* __restrict__ agg,
                        int n_dst)
{
    gather_body(x, rp, cnt, bucket, agg, n_dst, blockIdx.x);
}

__global__ void __launch_bounds__(256)
gather_mean_bf16_dual_kernel(const short8* __restrict__ xa,
                             const int* __restrict__ rpa, const int* __restrict__ cnta,
                             const int* __restrict__ bkta, short8* __restrict__ agga,
                             const short8* __restrict__ xb,
                             const int* __restrict__ rpb, const int* __restrict__ cntb,
                             const int* __restrict__ bktb, short8* __restrict__ aggb,
                             int n_dst, int na_blk)
{
    if ((int)blockIdx.x < na_blk)
        gather_body(xa, rpa, cnta, bkta, agga, n_dst, blockIdx.x);
    else
        gather_body(xb, rpb, cntb, bktb, aggb, n_dst, blockIdx.x - na_blk);
}

// ---------- MFMA epilogues (R19 mapping, verified absmax 0.0156) ------------
#define STAGE_ABF(DST, TBL, ROWID_EXPR)                                     \
    for (int idx = threadIdx.x; idx < 2048; idx += 256) {                   \
        int rr_ = idx >> 5, kk_ = idx & 31;                                 \
        ((u32*)&DST[rr_][0])[kk_] =                                         \
            ((const u32*)((TBL) + (size_t)(ROWID_EXPR) * 64))[kk_];         \
    }
#define STAGE_AF32(DST, SRCPTR_EXPR)                                        \
    for (int idx = threadIdx.x; idx < 4096; idx += 256) {                   \
        int r = idx >> 6, k = idx & 63;                                     \
        DST[r][k] = (short)f2bf((SRCPTR_EXPR)[k]);                          \
    }
#define STAGE_W1(DST, Wp)                                                   \
    for (int idx = threadIdx.x; idx < 4096; idx += 256) {                   \
        int j = idx >> 6, k = idx & 63;                                     \
        DST[j][k] = (short)f2bf((Wp)[idx]);                                 \
    }
#define STAGE_W2(DST, Wp, Wq)                                               \
    for (int idx = threadIdx.x; idx < 4096; idx += 256) {                   \
        int j = idx >> 6, k = idx & 63;                                     \
        DST[j][k] = (short)f2bf((Wp)[idx] + (Wq)[idx]);                     \
    }
#define MFMA_PHASE(ALDS, WLDS)                                              \
    _Pragma("unroll")                                                       \
    for (int kc = 0; kc < 2; ++kc) {                                        \
        short8 af = *(const short8*)&ALDS[lr0 + m][kc * 32 + kg * 8];       \
        _Pragma("unroll")                                                   \
        for (int nt = 0; nt < 4; ++nt) {                                    \
            short8 bf = *(const short8*)&WLDS[nt * 16 + m][kc * 32 + kg * 8];\
            acc[nt] = __builtin_amdgcn_mfma_f32_16x16x32_bf16(af, bf, acc[nt], 0, 0, 0); \
        }                                                                   \
    }

__global__ void __launch_bounds__(256)
epi_label_kernel(const u16b* __restrict__ agg_tl,
                 const u16b* __restrict__ agg_ll,
                 const u16b* __restrict__ lbf,
                 const int* __restrict__ nid,
                 const float* __restrict__ Wl_tl, const float* __restrict__ bl_tl,
                 const float* __restrict__ Wr_tl,
                 const float* __restrict__ Wl_ll, const float* __restrict__ bl_ll,
                 const float* __restrict__ Wr_ll,
                 float* __restrict__ out, int n)
{
    __shared__ short wa[64][72];
    __shared__ short w0[64][72];
    __shared__ short w1[64][72];
    __shared__ int   ndl[64];

    int tid = threadIdx.x;
    int base = blockIdx.x * 64;
    int lane = tid & 63;
    int m = lane & 15, kg = lane >> 4;
    int lr0 = (tid >> 6) * 16;

    if (tid < 64) ndl[tid] = nid[min(base + tid, n - 1)];
    STAGE_W1(w0, Wl_tl)
    STAGE_W1(w1, Wl_ll)
    STAGE_ABF(wa, agg_tl, min(base + rr_, n - 1))
    __syncthreads();

    f32x4 acc[4];
    #pragma unroll
    for (int nt = 0; nt < 4; ++nt) {
        float b = bl_tl[nt * 16 + m] + bl_ll[nt * 16 + m];
        acc[nt] = (f32x4){b, b, b, b};
    }

    MFMA_PHASE(wa, w0)
    __syncthreads();
    STAGE_ABF(wa, agg_ll, min(base + rr_, n - 1))
    __syncthreads();
    MFMA_PHASE(wa, w1)
    __syncthreads();
    STAGE_W2(w0, Wr_tl, Wr_ll)
    STAGE_ABF(wa, lbf, ndl[rr_])
    __syncthreads();
    MFMA_PHASE(wa, w0)

    #pragma unroll
    for (int nt = 0; nt < 4; ++nt) {
        #pragma unroll
        for (int j = 0; j < 4; ++j) {
            int gi = base + lr0 + kg * 4 + j;
            if (gi < n)
                out[(size_t)gi * 64 + nt * 16 + m] = fmaxf(acc[nt][j], 0.0f);
        }
    }
}

__global__ void __launch_bounds__(256)
epi_title_kernel(const u16b* __restrict__ agg_lt,
                 const float* __restrict__ title_x,
                 const float* __restrict__ Wl_tl, const float* __restrict__ bl_tl,
                 const float* __restrict__ Wr_tl,
                 float* __restrict__ out, int n)
{
    __shared__ short wa[64][72];
    __shared__ short w0[64][72];
    __shared__ short w1[64][72];

    int tid = threadIdx.x;
    int base = blockIdx.x * 64;
    int lane = tid & 63;
    int m = lane & 15, kg = lane >> 4;
    int lr0 = (tid >> 6) * 16;

    STAGE_W1(w0, Wl_tl)
    STAGE_W1(w1, Wr_tl)
    STAGE_ABF(wa, agg_lt, min(base + rr_, n - 1))
    __syncthreads();

    f32x4 acc[4];
    #pragma unroll
    for (int nt = 0; nt < 4; ++nt) {
        float b = bl_tl[nt * 16 + m];
        acc[nt] = (f32x4){b, b, b, b};
    }

    MFMA_PHASE(wa, w0)
    __syncthreads();
    STAGE_AF32(wa, title_x + (size_t)min(base + (idx >> 6), n - 1) * 64)
    __syncthreads();
    MFMA_PHASE(wa, w1)

    #pragma unroll
    for (int nt = 0; nt < 4; ++nt) {
        #pragma unroll
        for (int j = 0; j < 4; ++j) {
            int gi = base + lr0 + kg * 4 + j;
            if (gi < n)
                out[(size_t)gi * 64 + nt * 16 + m] = fmaxf(acc[nt][j], 0.0f);
        }
    }
}

extern "C" void kernel_launch(void* const* d_in, const int* in_sizes, int n_in,
                              void* d_out, int out_size, void* d_ws, size_t ws_size,
                              hipStream_t stream)
{
    const float* title_x   = (const float*)d_in[0];
    const float* label_emb = (const float*)d_in[1];
    const float* Wl_tl     = (const float*)d_in[2];
    const float* bl_tl     = (const float*)d_in[3];
    const float* Wr_tl     = (const float*)d_in[4];
    const float* Wl_ll     = (const float*)d_in[5];
    const float* bl_ll     = (const float*)d_in[6];
    const float* Wr_ll     = (const float*)d_in[7];
    const int* label_node_id = (const int*)d_in[8];
    const int* tl_src = (const int*)d_in[9];
    const int* tl_dst = (const int*)d_in[10];
    const int* lt_src = (const int*)d_in[11];
    const int* lt_dst = (const int*)d_in[12];
    const int* ll_src = (const int*)d_in[13];
    const int* ll_dst = (const int*)d_in[14];

    const int NT  = in_sizes[0] / 64;
    const int NL  = in_sizes[8];
    const int eTL = in_sizes[9];
    const int eLT = in_sizes[11];
    const int eLL = in_sizes[13];

    const int SH_L = 9,  NB_L = (NL + 511) >> 9;
    const int SH_T = 10, NB_T = (NT + 1023) >> 10;

    size_t szLbf  = (size_t)NL * 128;
    size_t szTbf  = (size_t)NT * 128;
    size_t szAgL  = (size_t)NL * 128;
    size_t szAgT  = (size_t)NT * 128;
    size_t iNL    = (size_t)NL * 4;
    size_t iNT    = (size_t)NT * 4;

    size_t regionA = szTbf + 2 * szAgL + 4 * iNL + ((size_t)eTL + eLL) * 4;
    size_t regionB = szAgT + 2 * iNT + (size_t)eLT * 4;
    size_t big     = regionA > regionB ? regionA : regionB;
    size_t szSmall = 2 * (256 + 257 + 256) * 4;   // dual binhist/start/cur
    size_t needed  = szLbf + big + szSmall;

    float* out_label = (float*)d_out;
    float* out_title = out_label + (size_t)NL * 64;

    if (ws_size < needed) {  // diagnosable: absmax ~999
        sentinel_kernel<<<(out_size + 255) / 256, 256, 0, stream>>>((float*)d_out, out_size);
        return;
    }

    char* base = (char*)d_ws;
    u16b* lbf = (u16b*)base;
    char* A0  = base + szLbf;
    u16b* tbf       = (u16b*)A0;
    u16b* agg_tl_bf = (u16b*)(A0 + szTbf);
    u16b* agg_ll_bf = (u16b*)(A0 + szTbf + szAgL);
    int* rp_tl  = (int*)(A0 + szTbf + 2 * szAgL);
    int* cnt_tl = rp_tl + NL;
    int* rp_ll  = cnt_tl + NL;
    int* cnt_ll = rp_ll + NL;
    int* bkt_tl = (int*)(A0 + szTbf + 2 * szAgL + 4 * iNL);
    int* bkt_ll = bkt_tl + eTL;
    // phase-A staging: two slices of the (dead) agg region: eTL+eLL ints fit
    u32* stagTL = (u32*)agg_tl_bf;
    u32* stagLL = stagTL + eTL;
    // phase B (overlays A0; stream-ordered)
    u16b* agg_lt_bf = (u16b*)A0;
    int* rp_lt  = (int*)(A0 + szAgT);
    int* cnt_lt = rp_lt + NT;
    int* bkt_lt = (int*)(A0 + szAgT + 2 * iNT);
    u32* stagB  = (u32*)A0;
    // small tail: A-set then B-set
    int* binhistA = (int*)(base + szLbf + big);
    int* binhistB = binhistA + 256;
    int* startA   = binhistB + 256;
    int* startB   = startA + 257;
    int* curA     = startB + 257;
    int* curB     = curA + 256;

    auto nchunk = [](int n) { return (n + 4095) / 4096; };

    // ---- prep: both bf16 tables, one dispatch ------------------------------
    int n4t = NT * 16, n4l = NL * 16;
    cvt_bf16_dual_kernel<<<2048 + 1024, 256, 0, stream>>>(
        (const float4*)title_x,   (ushort4*)tbf, n4t, 2048,
        (const float4*)label_emb, (ushort4*)lbf, n4l, 1024);

    // ---- phase A: label destination (tl + ll merged per stage) -------------
    int nchTL = nchunk(eTL), nchLL = nchunk(eLL);
    (void)hipMemsetAsync(binhistA, 0, 512 * 4, stream);   // both binhists
    bin_hist_dual_kernel<<<nchTL + nchLL, 256, 0, stream>>>(
        tl_dst, binhistA, eTL, nchTL, ll_dst, binhistB, eLL, SH_L);
    bin_scan_dual_kernel<<<2, 256, 0, stream>>>(
        binhistA, startA, curA, binhistB, startB, curB, NB_L);
    bin_scatter_dual_kernel<<<nchTL + nchLL, 256, 0, stream>>>(
        tl_src, tl_dst, curA, stagTL, eTL, nchTL,
        ll_src, ll_dst, label_node_id, curB, stagLL, eLL, SH_L);
    bin_build_dual_kernel<<<2 * NB_L, 256, 0, stream>>>(
        stagTL, startA, bkt_tl, rp_tl, cnt_tl,
        stagLL, startB, bkt_ll, rp_ll, cnt_ll, SH_L, NL, NB_L);
    int nblkL = (NL + 7) / 8;
    gather_mean_bf16_dual_kernel<<<2 * nblkL, 256, 0, stream>>>(
        (const short8*)tbf, rp_tl, cnt_tl, bkt_tl, (short8*)agg_tl_bf,
        (const short8*)lbf, rp_ll, cnt_ll, bkt_ll, (short8*)agg_ll_bf,
        NL, nblkL);
    epi_label_kernel<<<(NL + 63) / 64, 256, 0, stream>>>(
        agg_tl_bf, agg_ll_bf, lbf, label_node_id,
        Wl_tl, bl_tl, Wr_tl, Wl_ll, bl_ll, Wr_ll, out_label, NL);

    // ---- phase B: title destination (stream-ordered reuse) -----------------
    (void)hipMemsetAsync(binhistA, 0, 256 * 4, stream);
    bin_hist_kernel<<<nchunk(eLT), 256, 0, stream>>>(lt_dst, binhistA, eLT, SH_T);
    bin_scan_kernel<<<1, 256, 0, stream>>>(binhistA, startA, curA, NB_T);
    bin_scatter_kernel<<<nchunk(eLT), 256, 0, stream>>>(
        lt_src, lt_dst, label_node_id, curA, stagB, eLT, SH_T);
    bin_build_kernel<<<NB_T, 256, 0, stream>>>(
        stagB, startA, bkt_lt, rp_lt, cnt_lt, SH_T, NT);
    gather_mean_bf16_kernel<<<(NT + 7) / 8, 256, 0, stream>>>(
        (const short8*)lbf, rp_lt, cnt_lt, bkt_lt, (short8*)agg_lt_bf, NT);
    epi_title_kernel<<<(NT + 63) / 64, 256, 0, stream>>>(
        agg_lt_bf, title_x, Wl_tl, bl_tl, Wr_tl, out_title, NT);
}